// Round 9
// baseline (1560.896 us; speedup 1.0000x reference)
//
#include <hip/hip_runtime.h>

typedef unsigned short u16;
typedef unsigned int u32;
typedef __bf16 bf16x8 __attribute__((ext_vector_type(8)));
typedef float f32x4 __attribute__((ext_vector_type(4)));
typedef u16 u16x8 __attribute__((ext_vector_type(8)));
typedef u16 u16x4 __attribute__((ext_vector_type(4)));
typedef u32 u32x4 __attribute__((ext_vector_type(4)));

__device__ __forceinline__ u16 f2bf(float f){
  unsigned u = __float_as_uint(f);
  u += 0x7FFFu + ((u >> 16) & 1u);   // RNE
  return (u16)(u >> 16);
}
__device__ __forceinline__ u32 pack2bf(float a, float b){
  return (u32)f2bf(a) | ((u32)f2bf(b) << 16);
}
__device__ __forceinline__ void gload16(const void* g, void* l){
  __builtin_amdgcn_global_load_lds(
      (const __attribute__((address_space(1))) void*)g,
      (__attribute__((address_space(3))) void*)l, 16, 0, 0);
}

// ---------------- weight f32 [K][N] -> bf16 [drow0+N][K] (transposing convert) ----------------
__global__ __launch_bounds__(256) void conv_bf16_t(const float* __restrict__ src, u16* __restrict__ dst,
                                                   int K, int N, size_t dls, int drow0){
  __shared__ u16 s[64 * 68];
  size_t lo = (size_t)blockIdx.z * K * N;
  int n0 = blockIdx.x << 6, k0 = blockIdx.y << 6;
  int t = threadIdx.x;
#pragma unroll
  for (int p = 0; p < 4; ++p){
    int idx = p * 1024 + t * 4;
    int kl = idx >> 6, nl = idx & 63;
    f32x4 v = *(const f32x4*)(src + lo + (size_t)(k0 + kl) * N + n0 + nl);
#pragma unroll
    for (int j = 0; j < 4; ++j) s[(nl + j) * 68 + kl] = f2bf(v[j]);
  }
  __syncthreads();
  u16* db = dst + blockIdx.z * dls;
#pragma unroll
  for (int p = 0; p < 4; ++p){
    int idx = p * 1024 + t * 4;
    int nl = idx >> 6, kl = idx & 63;
    u16x4 o;
#pragma unroll
    for (int j = 0; j < 4; ++j) o[j] = s[nl * 68 + kl + j];
    *(u16x4*)(db + (size_t)(drow0 + n0 + nl) * K + k0 + kl) = o;
  }
}

// ---------------- plain f32 -> bf16 ----------------
__global__ __launch_bounds__(256) void conv_bf16(const float* __restrict__ src, u16* __restrict__ dst){
  size_t i = ((size_t)blockIdx.x * 256 + threadIdx.x) * 4;
  f32x4 v = *(const f32x4*)(src + i);
  u16x4 o;
#pragma unroll
  for (int j = 0; j < 4; ++j) o[j] = f2bf(v[j]);
  *(u16x4*)(dst + i) = o;
}

// ---------------- embedding + positional encoding ----------------
__global__ __launch_bounds__(256) void embed_k(const int* __restrict__ data, const float* __restrict__ emb,
                                               float* __restrict__ h, u16* __restrict__ hbf){
  int idx = blockIdx.x * 256 + threadIdx.x;       // 0 .. 2M-1
  int r = idx >> 10, d = idx & 1023;              // r = i*4+b
  int i = r >> 2;
  int e = data[r];
  float val = emb[(size_t)e * 1024 + d] * 32.0f;  // sqrt(1024)
  float pos = (float)(511 - i);
  int t = d & 511;
  float freq = powf(10000.0f, -(float)t * (1.0f / 512.0f));
  float ang = pos * freq;
  val += (d < 512) ? sinf(ang) : cosf(ang);
  h[idx] = val;
  hbf[idx] = f2bf(val);
}

// ---------------- bf16 MFMA GEMM: C = A[M,K] @ Bt[N,K]^T ----------------
// BK=64 (half the barriers of BK=32), 2-buffer R5 schedule, row&7 slot swizzle
// (128B rows: bank = slot only -> must swizzle slot by row; both-sides rule).
// blockIdx.z = K-chunk (if Cpart) or batch (zA/zB/zC strides).
template<int BM>
__global__ __launch_bounds__(256) void gemm_bt(
    const u16* __restrict__ A, const u16* __restrict__ Bt,
    const float* __restrict__ bias, float* __restrict__ C, u16* __restrict__ Cbf,
    float* __restrict__ Cpart, int M, int N, int K, int kchunk, int relu,
    size_t zA, size_t zB, size_t zC)
{
  constexpr int MFR = BM / 32;            // A frags per wave
  constexpr int ASZ = BM * 64, BSZ = 128 * 64;   // elements per buffer
  __shared__ __align__(16) u16 sA[2 * ASZ];
  __shared__ __align__(16) u16 sB[2 * BSZ];
  int tid = threadIdx.x, lane = tid & 63;
  int wr = (tid >> 7) & 1, wc = (tid >> 6) & 1;
  int m0 = blockIdx.y * BM, n0 = blockIdx.x << 7;
  int z = blockIdx.z;
  int kbeg = Cpart ? z * kchunk : 0;

  const u16* Ap = A + (size_t)z * zA;
  const u16* Bp = Bt + (size_t)z * zB;

  f32x4 acc[MFR][4];
#pragma unroll
  for (int i = 0; i < MFR; ++i)
#pragma unroll
    for (int j = 0; j < 4; ++j) acc[i][j] = (f32x4)(0.0f);

  // staging: thread t handles row (t>>3)+32p, 16B slot (t&7); LDS slot holds
  // global slot (t&7)^(row&7) (pre-swizzled source, same 128B row -> coalesced)
  int srow8 = tid >> 3;                   // 0..31
  int gslot8 = ((tid & 7) ^ (srow8 & 7)) << 3;
  const u16* Ab = Ap + (size_t)(m0 + srow8) * K + kbeg + gslot8;
  const u16* Bb = Bp + (size_t)(n0 + srow8) * K + kbeg + gslot8;
  const size_t rstep32 = (size_t)K << 5;  // 32 rows

  auto stage = [&](int buf, int k0){
#pragma unroll
    for (int p = 0; p < BM / 32; ++p)
      gload16(Ab + p * rstep32 + k0, (void*)&sA[buf * ASZ + p * 2048 + tid * 8]);
#pragma unroll
    for (int p = 0; p < 4; ++p)
      gload16(Bb + p * rstep32 + k0, (void*)&sB[buf * BSZ + p * 2048 + tid * 8]);
  };

  // fragment read slots: global slot g (kk=0) / g+4 (kk=1) of row r15 lives at
  // LDS slot (g^(r15&7)) / that^4. All row offsets (16*mi, 32*wr, 64*wc) are ==0 mod 8.
  int r15 = lane & 15, g = lane >> 4;
  int s0 = g ^ (r15 & 7);
  const int o0 = s0 * 8, o1 = (s0 ^ 4) * 8;
  const int paBase = (wr * (BM / 2) + r15) * 64;
  const int pbBase = (wc * 64 + r15) * 64;

  int nk = kchunk >> 6;
  stage(0, 0);
  __syncthreads();
  for (int t = 0; t < nk; ++t){
    int cur = t & 1;
    if (t + 1 < nk) stage(cur ^ 1, (t + 1) << 6);
    const u16* pa = sA + cur * ASZ;
    const u16* pb = sB + cur * BSZ;
    bf16x8 af[MFR][2], bfv[4][2];
#pragma unroll
    for (int mi = 0; mi < MFR; ++mi){
      af[mi][0] = *(const bf16x8*)(pa + paBase + mi * 1024 + o0);
      af[mi][1] = *(const bf16x8*)(pa + paBase + mi * 1024 + o1);
    }
#pragma unroll
    for (int ni = 0; ni < 4; ++ni){
      bfv[ni][0] = *(const bf16x8*)(pb + pbBase + ni * 1024 + o0);
      bfv[ni][1] = *(const bf16x8*)(pb + pbBase + ni * 1024 + o1);
    }
#pragma unroll
    for (int kk = 0; kk < 2; ++kk)
#pragma unroll
      for (int mi = 0; mi < MFR; ++mi)
#pragma unroll
        for (int ni = 0; ni < 4; ++ni)
          acc[mi][ni] = __builtin_amdgcn_mfma_f32_16x16x32_bf16(af[mi][kk], bfv[ni][kk], acc[mi][ni], 0, 0, 0);
    __syncthreads();
  }

  int colf = lane & 15, rowf = (lane >> 4) << 2;
  if (Cpart){
    float* dst = Cpart + (size_t)z * M * N;
#pragma unroll
    for (int ni = 0; ni < 4; ++ni){
      int cg = n0 + (wc << 6) + ni * 16 + colf;
#pragma unroll
      for (int mi = 0; mi < MFR; ++mi){
        int rg = m0 + wr * (BM / 2) + mi * 16 + rowf;
#pragma unroll
        for (int r = 0; r < 4; ++r)
          dst[(size_t)(rg + r) * N + cg] = acc[mi][ni][r];
      }
    }
  } else {
#pragma unroll
    for (int ni = 0; ni < 4; ++ni){
      int cg = n0 + (wc << 6) + ni * 16 + colf;
      float bv = bias ? bias[cg] : 0.0f;
#pragma unroll
      for (int mi = 0; mi < MFR; ++mi){
        int rg = m0 + wr * (BM / 2) + mi * 16 + rowf;
#pragma unroll
        for (int r = 0; r < 4; ++r){
          float val = acc[mi][ni][r] + bv;
          if (relu) val = fmaxf(val, 0.0f);
          size_t o = (size_t)(rg + r) * N + cg;
          if (C)   C[o]   = val;
          if (Cbf) (Cbf + (size_t)z * zC)[o] = f2bf(val);
        }
      }
    }
  }
}

// ---------------- V transpose into vtbf [bn][d][jdst0 + j] ----------------
__global__ __launch_bounds__(256) void vtrans(const u16* __restrict__ src, int sstride, int co,
                                              u16* __restrict__ dst, int jdst0,
                                              size_t zsrc, size_t zdst){
  __shared__ u16 s[64 * 68];
  int jt = blockIdx.x, bnp = blockIdx.y;
  int b = bnp >> 4, n = bnp & 15;
  int t = threadIdx.x;
  const u16* sp = src + blockIdx.z * zsrc;
  u16* dp = dst + blockIdx.z * zdst;
  int j0l = jt << 6;
#pragma unroll
  for (int rr = 0; rr < 16; ++rr){
    int idx = rr * 256 + t;
    int jl = idx >> 6, dd = idx & 63;
    s[jl * 68 + dd] = sp[(size_t)((j0l + jl) * 4 + b) * sstride + co + n * 128 + 64 + dd];
  }
  __syncthreads();
#pragma unroll
  for (int ww = 0; ww < 16; ++ww){
    int idx = ww * 256 + t;
    int dd = idx >> 6, jl = idx & 63;
    dp[((size_t)(bnp * 64 + dd) << 10) + jdst0 + j0l + jl] = s[jl * 68 + dd];
  }
}

// ---------------- MFMA flash attention, KV-split (blockIdx.z = half) ----------------
__global__ __launch_bounds__(256) void attn_mfma_split(
    const u16* __restrict__ qkv, const u16* __restrict__ kvm,
    const u16* __restrict__ vtbf, float* __restrict__ obuf, float* __restrict__ mlbuf)
{
  int tid = threadIdx.x, lane = tid & 63, wid = tid >> 6;
  int g = lane >> 4, t = lane & 15;
  int qt = blockIdx.x, bnp = blockIdx.y, half = blockIdx.z;
  int b = bnp >> 4, n = bnp & 15;
  int i0 = qt * 64 + wid * 16;
  int i = i0 + t;

  union Cvt { u32x4 u; bf16x8 v; };

  bf16x8 qfrag[2];
#pragma unroll
  for (int ks = 0; ks < 2; ++ks)
    qfrag[ks] = *(const bf16x8*)(qkv + (size_t)(i * 4 + b) * 3072 + n * 64 + ks * 32 + g * 8);

  f32x4 oacc[4];
#pragma unroll
  for (int df = 0; df < 4; ++df) oacc[df] = (f32x4)(0.0f);
  float mrun = -1e30f, lrun = 0.0f;

  const u16* kb; size_t kst; int joff, kt0, kt1;
  if (half == 0){ kb = kvm + n * 128;        kst = 2048; joff = 0;   kt0 = 0; kt1 = 8; }
  else          { kb = qkv + 1024 + n * 128; kst = 3072; joff = 512; kt0 = 8; kt1 = ((i0 + 527) >> 6) + 1; }

  for (int kt = kt0; kt < kt1; ++kt){
    int j0 = kt << 6;
    f32x4 sacc[4];
#pragma unroll
    for (int jf = 0; jf < 4; ++jf) sacc[jf] = (f32x4)(0.0f);
#pragma unroll
    for (int ks = 0; ks < 2; ++ks){
#pragma unroll
      for (int jf = 0; jf < 4; ++jf){
        int j = j0 + jf * 16 + t - joff;
        bf16x8 kf = *(const bf16x8*)(kb + (size_t)(j * 4 + b) * kst + ks * 32 + g * 8);
        sacc[jf] = __builtin_amdgcn_mfma_f32_16x16x32_bf16(kf, qfrag[ks], sacc[jf], 0, 0, 0);
      }
    }
    bool part = (half == 1) && (j0 + 63 > i0 + 512);
    float ps[4][4];
    float tmax = -1e30f;
#pragma unroll
    for (int jf = 0; jf < 4; ++jf)
#pragma unroll
      for (int r = 0; r < 4; ++r){
        float s = sacc[jf][r] * 0.125f;
        if (part && (j0 + jf * 16 + g * 4 + r > i + 512)) s = -1e30f;
        ps[jf][r] = s;
        tmax = fmaxf(tmax, s);
      }
    tmax = fmaxf(tmax, __shfl_xor(tmax, 16));
    tmax = fmaxf(tmax, __shfl_xor(tmax, 32));
    float mnew = fmaxf(mrun, tmax);
    float sc = __expf(mrun - mnew);
    mrun = mnew;
    lrun *= sc;
    u32 pk0[2], pk1[2], pk2[2], pk3[2];
    {
      float e0, e1, e2, e3;
#define DO_JF(PK, JF) \
      e0 = __expf(ps[JF][0] - mnew); e1 = __expf(ps[JF][1] - mnew); \
      e2 = __expf(ps[JF][2] - mnew); e3 = __expf(ps[JF][3] - mnew); \
      lrun += (e0 + e1) + (e2 + e3); \
      PK[0] = pack2bf(e0, e1); PK[1] = pack2bf(e2, e3);
      DO_JF(pk0, 0) DO_JF(pk1, 1) DO_JF(pk2, 2) DO_JF(pk3, 3)
#undef DO_JF
    }
#pragma unroll
    for (int df = 0; df < 4; ++df)
#pragma unroll
      for (int r = 0; r < 4; ++r) oacc[df][r] *= sc;

    int srcA = t + 16 * ((2 * g) & 3);
    int srcB = t + 16 * ((2 * g + 1) & 3);
    bool ghi = (g >= 2);
#pragma unroll
    for (int ks = 0; ks < 2; ++ks){
      u32 w0a, w1a, w2a, w3a, w0b, w1b, w2b, w3b;
      if (ks == 0){
        w0a = __shfl((int)pk0[0], srcA); w1a = __shfl((int)pk0[1], srcA);
        w2a = __shfl((int)pk0[0], srcB); w3a = __shfl((int)pk0[1], srcB);
        w0b = __shfl((int)pk1[0], srcA); w1b = __shfl((int)pk1[1], srcA);
        w2b = __shfl((int)pk1[0], srcB); w3b = __shfl((int)pk1[1], srcB);
      } else {
        w0a = __shfl((int)pk2[0], srcA); w1a = __shfl((int)pk2[1], srcA);
        w2a = __shfl((int)pk2[0], srcB); w3a = __shfl((int)pk2[1], srcB);
        w0b = __shfl((int)pk3[0], srcA); w1b = __shfl((int)pk3[1], srcA);
        w2b = __shfl((int)pk3[0], srcB); w3b = __shfl((int)pk3[1], srcB);
      }
      Cvt c;
      c.u[0] = ghi ? w0b : w0a;
      c.u[1] = ghi ? w1b : w1a;
      c.u[2] = ghi ? w2b : w2a;
      c.u[3] = ghi ? w3b : w3a;
      bf16x8 pf = c.v;
#pragma unroll
      for (int df = 0; df < 4; ++df){
        bf16x8 vf = *(const bf16x8*)(vtbf + ((size_t)(bnp * 64 + df * 16 + t) << 10) + j0 + ks * 32 + g * 8);
        oacc[df] = __builtin_amdgcn_mfma_f32_16x16x32_bf16(vf, pf, oacc[df], 0, 0, 0);
      }
    }
  }
  lrun += __shfl_xor(lrun, 16);
  lrun += __shfl_xor(lrun, 32);

  float* orow = obuf + ((size_t)(half * 2048 + i * 4 + b) << 10) + n * 64;
#pragma unroll
  for (int df = 0; df < 4; ++df){
#pragma unroll
    for (int h = 0; h < 2; ++h){
      orow[df * 16 + g * 4 + 2 * h]     = oacc[df][2 * h];
      orow[df * 16 + g * 4 + 2 * h + 1] = oacc[df][2 * h + 1];
    }
  }
  if (g == 0){
    float* ml = mlbuf + (((size_t)(half * 2048 + i * 4 + b)) * 16 + n) * 2;
    ml[0] = mrun; ml[1] = lrun;
  }
}

// ---------------- merge the two KV halves (log-sum-exp weighting) ----------------
__global__ __launch_bounds__(256) void attn_merge(const float* __restrict__ obuf,
                                                  const float* __restrict__ mlbuf,
                                                  u16* __restrict__ attnbf){
  int r = blockIdx.x, tid = threadIdx.x;
  int d0 = tid * 4, n = tid >> 4;
  const float* ml0 = mlbuf + ((size_t)r * 16 + n) * 2;
  const float* ml1 = mlbuf + ((size_t)(2048 + r) * 16 + n) * 2;
  float m0 = ml0[0], l0 = ml0[1], m1 = ml1[0], l1 = ml1[1];
  float M = fmaxf(m0, m1);
  float w0 = __expf(m0 - M), w1 = __expf(m1 - M);
  float inv = 1.0f / (w0 * l0 + w1 * l1);
  f32x4 o0 = *(const f32x4*)(obuf + ((size_t)r << 10) + d0);
  f32x4 o1 = *(const f32x4*)(obuf + ((size_t)(2048 + r) << 10) + d0);
  u16x4 o;
#pragma unroll
  for (int j = 0; j < 4; ++j) o[j] = f2bf((w0 * o0[j] + w1 * o1[j]) * inv);
  *(u16x4*)(attnbf + ((size_t)r << 10) + d0) = o;
}

// ---------------- residual + (split-K partial sum) + bias + layernorm ----------------
__global__ __launch_bounds__(256) void ln_k(const float* __restrict__ res, const float* __restrict__ parts,
                                            size_t pstride, int np, const float* __restrict__ bias,
                                            const float* __restrict__ g, const float* __restrict__ bta,
                                            float* hout, u16* __restrict__ hbf)
{
  int row = blockIdx.x, tid = threadIdx.x;
  const float* rr = res + ((size_t)row << 10);
  float v[4]; float s = 0.0f, s2 = 0.0f;
#pragma unroll
  for (int k = 0; k < 4; ++k){
    int d = tid + (k << 8);
    float t = rr[d] + (bias ? bias[d] : 0.0f);
    for (int p = 0; p < np; ++p) t += parts[p * pstride + ((size_t)row << 10) + d];
    v[k] = t; s += t; s2 += t * t;
  }
#pragma unroll
  for (int off = 32; off; off >>= 1){ s += __shfl_xor(s, off); s2 += __shfl_xor(s2, off); }
  __shared__ float ps[8];
  int wid = tid >> 6, lane = tid & 63;
  if (lane == 0){ ps[wid] = s; ps[wid + 4] = s2; }
  __syncthreads();
  s  = ps[0] + ps[1] + ps[2] + ps[3];
  s2 = ps[4] + ps[5] + ps[6] + ps[7];
  float mu = s * 0.0009765625f;
  float var = s2 * 0.0009765625f - mu * mu;
  float rstd = rsqrtf(var + 1e-5f);
  float* ho = hout + ((size_t)row << 10);
  u16* hb = hbf + ((size_t)row << 10);
#pragma unroll
  for (int k = 0; k < 4; ++k){
    int d = tid + (k << 8);
    float t = (v[k] - mu) * rstd * g[d] + bta[d];
    ho[d] = t; hb[d] = f2bf(t);
  }
}

__global__ __launch_bounds__(256) void copy_f32(const f32x4* __restrict__ src, f32x4* __restrict__ dst){
  size_t i = (size_t)blockIdx.x * 256 + threadIdx.x;
  dst[i] = src[i];
}

extern "C" void kernel_launch(void* const* d_in, const int* in_sizes, int n_in,
                              void* d_out, int out_size, void* d_ws, size_t ws_size,
                              hipStream_t stream)
{
  const int*   data = (const int*)  d_in[0];
  const float* mems = (const float*)d_in[1];
  const float* emb  = (const float*)d_in[2];
  const float* Wq   = (const float*)d_in[3];
  const float* Wkv  = (const float*)d_in[4];
  const float* Wo   = (const float*)d_in[5];
  const float* ln1g = (const float*)d_in[6];
  const float* ln1b = (const float*)d_in[7];
  const float* W1   = (const float*)d_in[8];
  const float* b1   = (const float*)d_in[9];
  const float* W2   = (const float*)d_in[10];
  const float* b2   = (const float*)d_in[11];
  const float* ln2g = (const float*)d_in[12];
  const float* ln2b = (const float*)d_in[13];
  float* out = (float*)d_out;

  char* ws = (char*)d_ws;
  size_t off = 0;
  auto alloc = [&](size_t bytes) -> char* {
    char* p = ws + off;
    off = (off + bytes + 255) & ~(size_t)255;
    return p;
  };

  // fused transposed QKV weights: [l][3072][1024] (rows 0..1023 = Wq^T, 1024..3071 = Wkv^T)
  u16*   wqkv_bf = (u16*) alloc((size_t)6 * 3072 * 1024 * 2);
  u16*   wo_bf   = (u16*) alloc((size_t)6 * 1024 * 1024 * 2);
  u16*   w1_bf   = (u16*) alloc((size_t)6 * 4096 * 1024 * 2);
  u16*   w2_bf   = (u16*) alloc((size_t)6 * 1024 * 4096 * 2);
  u16*   memsbf  = (u16*) alloc((size_t)6 * 2048 * 1024 * 2);
  u16*   kvmem   = (u16*) alloc((size_t)6 * 2048 * 2048 * 2);   // per-layer mems-KV
  u16*   vtbf    = (u16*) alloc((size_t)6 * 64 * 64 * 1024 * 2);
  float* h       = (float*)alloc((size_t)2048 * 1024 * 4);
  u16*   hbf     = (u16*) alloc((size_t)2048 * 1024 * 2);
  u16*   qkv     = (u16*) alloc((size_t)2048 * 3072 * 2);
  u16*   attnbf  = (u16*) alloc((size_t)2048 * 1024 * 2);
  u16*   f1bf    = (u16*) alloc((size_t)2048 * 4096 * 2);
  float* pbuf    = (float*)alloc((size_t)4 * 2048 * 1024 * 4);  // split-K partials / attn halves
  float* mlbuf   = (float*)alloc((size_t)2 * 2048 * 16 * 2 * 4);
  const size_t PS = (size_t)2048 * 1024;
  const size_t VTL = (size_t)64 * 64 * 1024;

  // ---- layer-independent preamble (full-chip parallel) ----
  conv_bf16_t<<<dim3(16, 16, 6), 256, 0, stream>>>(Wq,  wqkv_bf, 1024, 1024, (size_t)3072 * 1024, 0);
  conv_bf16_t<<<dim3(32, 16, 6), 256, 0, stream>>>(Wkv, wqkv_bf, 1024, 2048, (size_t)3072 * 1024, 1024);
  conv_bf16_t<<<dim3(16, 16, 6), 256, 0, stream>>>(Wo,  wo_bf,   1024, 1024, (size_t)1024 * 1024, 0);
  conv_bf16_t<<<dim3(64, 16, 6), 256, 0, stream>>>(W1,  w1_bf,   1024, 4096, (size_t)4096 * 1024, 0);
  conv_bf16_t<<<dim3(16, 64, 6), 256, 0, stream>>>(W2,  w2_bf,   4096, 1024, (size_t)4096 * 1024, 0);
  conv_bf16<<<12288, 256, 0, stream>>>(mems, memsbf);
  embed_k<<<8192, 256, 0, stream>>>(data, emb, h, hbf);
  // batched mems-KV GEMM for all 6 layers: kvmem[l] = memsbf[l] @ Wkv[l]
  gemm_bt<64><<<dim3(16, 32, 6), 256, 0, stream>>>(memsbf, wqkv_bf + (size_t)1024 * 1024, nullptr,
      nullptr, kvmem, nullptr, 2048, 2048, 1024, 1024, 0,
      (size_t)2048 * 1024, (size_t)3072 * 1024, (size_t)2048 * 2048);
  // mems-V transpose for all layers (j < 512)
  vtrans<<<dim3(8, 64, 6), 256, 0, stream>>>(kvmem, 2048, 0, vtbf, 0, (size_t)2048 * 2048, VTL);

  for (int l = 0; l < 6; ++l){
    u16* kvm_l = kvmem + (size_t)l * 2048 * 2048;
    u16* vt_l  = vtbf + (size_t)l * VTL;
    // fused Q/KV(h) GEMM: qkv[2048][3072]
    gemm_bt<64><<<dim3(24, 32), 256, 0, stream>>>(hbf, wqkv_bf + (size_t)l * 3072 * 1024, nullptr,
        nullptr, qkv, nullptr, 2048, 3072, 1024, 1024, 0, 0, 0, 0);
    // h-part V transpose (j >= 512)
    vtrans<<<dim3(8, 64), 256, 0, stream>>>(qkv, 3072, 1024, vt_l, 512, 0, 0);
    // attention: 2 KV-halves in parallel, then merge
    attn_mfma_split<<<dim3(8, 64, 2), 256, 0, stream>>>(qkv, kvm_l, vt_l, pbuf, mlbuf);
    attn_merge<<<2048, 256, 0, stream>>>(pbuf, mlbuf, attnbf);
    // Wo: split-K x2, summed inside ln1 (pbuf reused after merge consumed it)
    gemm_bt<64><<<dim3(8, 32, 2), 256, 0, stream>>>(attnbf, wo_bf + (size_t)l * 1024 * 1024, nullptr,
        nullptr, nullptr, pbuf, 2048, 1024, 1024, 512, 0, 0, 0, 0);
    ln_k<<<2048, 256, 0, stream>>>(h, pbuf, PS, 2, nullptr, ln1g + l * 1024, ln1b + l * 1024, h, hbf);
    // W1 + bias + relu
    gemm_bt<64><<<dim3(32, 32), 256, 0, stream>>>(hbf, w1_bf + (size_t)l * 4096 * 1024,
        b1 + (size_t)l * 4096, nullptr, f1bf, nullptr, 2048, 4096, 1024, 1024, 1, 0, 0, 0);
    // W2: split-K x4, summed (+b2) inside ln2
    gemm_bt<64><<<dim3(8, 32, 4), 256, 0, stream>>>(f1bf, w2_bf + (size_t)l * 4096 * 1024, nullptr,
        nullptr, nullptr, pbuf, 2048, 1024, 4096, 1024, 0, 0, 0, 0);
    ln_k<<<2048, 256, 0, stream>>>(h, pbuf, PS, 4, b2 + l * 1024, ln2g + l * 1024, ln2b + l * 1024, h, hbf);
  }
  copy_f32<<<2048, 256, 0, stream>>>((const f32x4*)h, (f32x4*)out);
}

// Round 10
// 1219.034 us; speedup vs baseline: 1.2804x; 1.2804x over previous
//
#include <hip/hip_runtime.h>

typedef unsigned short u16;
typedef unsigned int u32;
typedef __bf16 bf16x8 __attribute__((ext_vector_type(8)));
typedef float f32x4 __attribute__((ext_vector_type(4)));
typedef u16 u16x8 __attribute__((ext_vector_type(8)));
typedef u16 u16x4 __attribute__((ext_vector_type(4)));
typedef u32 u32x4 __attribute__((ext_vector_type(4)));

__device__ __forceinline__ u16 f2bf(float f){
  unsigned u = __float_as_uint(f);
  u += 0x7FFFu + ((u >> 16) & 1u);   // RNE
  return (u16)(u >> 16);
}
__device__ __forceinline__ float bf2f(u16 u){
  return __uint_as_float((u32)u << 16);
}
__device__ __forceinline__ u32 pack2bf(float a, float b){
  return (u32)f2bf(a) | ((u32)f2bf(b) << 16);
}
__device__ __forceinline__ void gload16(const void* g, void* l){
  __builtin_amdgcn_global_load_lds(
      (const __attribute__((address_space(1))) void*)g,
      (__attribute__((address_space(3))) void*)l, 16, 0, 0);
}

// ---------------- weight f32 [K][N] -> bf16 [drow0+N][K] (transposing convert) ----------------
__global__ __launch_bounds__(256) void conv_bf16_t(const float* __restrict__ src, u16* __restrict__ dst,
                                                   int K, int N, size_t dls, int drow0){
  __shared__ u16 s[64 * 68];
  size_t lo = (size_t)blockIdx.z * K * N;
  int n0 = blockIdx.x << 6, k0 = blockIdx.y << 6;
  int t = threadIdx.x;
#pragma unroll
  for (int p = 0; p < 4; ++p){
    int idx = p * 1024 + t * 4;
    int kl = idx >> 6, nl = idx & 63;
    f32x4 v = *(const f32x4*)(src + lo + (size_t)(k0 + kl) * N + n0 + nl);
#pragma unroll
    for (int j = 0; j < 4; ++j) s[(nl + j) * 68 + kl] = f2bf(v[j]);
  }
  __syncthreads();
  u16* db = dst + blockIdx.z * dls;
#pragma unroll
  for (int p = 0; p < 4; ++p){
    int idx = p * 1024 + t * 4;
    int nl = idx >> 6, kl = idx & 63;
    u16x4 o;
#pragma unroll
    for (int j = 0; j < 4; ++j) o[j] = s[nl * 68 + kl + j];
    *(u16x4*)(db + (size_t)(drow0 + n0 + nl) * K + k0 + kl) = o;
  }
}

// ---------------- plain f32 -> bf16 ----------------
__global__ __launch_bounds__(256) void conv_bf16(const float* __restrict__ src, u16* __restrict__ dst){
  size_t i = ((size_t)blockIdx.x * 256 + threadIdx.x) * 4;
  f32x4 v = *(const f32x4*)(src + i);
  u16x4 o;
#pragma unroll
  for (int j = 0; j < 4; ++j) o[j] = f2bf(v[j]);
  *(u16x4*)(dst + i) = o;
}

// ---------------- embedding + positional encoding ----------------
__global__ __launch_bounds__(256) void embed_k(const int* __restrict__ data, const float* __restrict__ emb,
                                               float* __restrict__ h, u16* __restrict__ hbf){
  int idx = blockIdx.x * 256 + threadIdx.x;       // 0 .. 2M-1
  int r = idx >> 10, d = idx & 1023;              // r = i*4+b
  int i = r >> 2;
  int e = data[r];
  float val = emb[(size_t)e * 1024 + d] * 32.0f;  // sqrt(1024)
  float pos = (float)(511 - i);
  int t = d & 511;
  float freq = powf(10000.0f, -(float)t * (1.0f / 512.0f));
  float ang = pos * freq;
  val += (d < 512) ? sinf(ang) : cosf(ang);
  h[idx] = val;
  hbf[idx] = f2bf(val);
}

// ---------------- bf16 MFMA GEMM: C = A[M,K] @ Bt[N,K]^T ----------------
// BK=64, 2-buffer R5 schedule, row&7 slot swizzle (both-sides). Cpart = bf16 partials.
// blockIdx.z = K-chunk (if Cpart) or batch (zA/zB/zC strides).
template<int BM>
__global__ __launch_bounds__(256) void gemm_bt(
    const u16* __restrict__ A, const u16* __restrict__ Bt,
    const float* __restrict__ bias, float* __restrict__ C, u16* __restrict__ Cbf,
    u16* __restrict__ Cpart, int M, int N, int K, int kchunk, int relu,
    size_t zA, size_t zB, size_t zC)
{
  constexpr int MFR = BM / 32;            // A frags per wave
  constexpr int ASZ = BM * 64, BSZ = 128 * 64;   // elements per buffer
  __shared__ __align__(16) u16 sA[2 * ASZ];
  __shared__ __align__(16) u16 sB[2 * BSZ];
  int tid = threadIdx.x, lane = tid & 63;
  int wr = (tid >> 7) & 1, wc = (tid >> 6) & 1;
  int m0 = blockIdx.y * BM, n0 = blockIdx.x << 7;
  int z = blockIdx.z;
  int kbeg = Cpart ? z * kchunk : 0;

  const u16* Ap = A + (size_t)z * zA;
  const u16* Bp = Bt + (size_t)z * zB;

  f32x4 acc[MFR][4];
#pragma unroll
  for (int i = 0; i < MFR; ++i)
#pragma unroll
    for (int j = 0; j < 4; ++j) acc[i][j] = (f32x4)(0.0f);

  int srow8 = tid >> 3;                   // 0..31
  int gslot8 = ((tid & 7) ^ (srow8 & 7)) << 3;
  const u16* Ab = Ap + (size_t)(m0 + srow8) * K + kbeg + gslot8;
  const u16* Bb = Bp + (size_t)(n0 + srow8) * K + kbeg + gslot8;
  const size_t rstep32 = (size_t)K << 5;  // 32 rows

  auto stage = [&](int buf, int k0){
#pragma unroll
    for (int p = 0; p < BM / 32; ++p)
      gload16(Ab + p * rstep32 + k0, (void*)&sA[buf * ASZ + p * 2048 + tid * 8]);
#pragma unroll
    for (int p = 0; p < 4; ++p)
      gload16(Bb + p * rstep32 + k0, (void*)&sB[buf * BSZ + p * 2048 + tid * 8]);
  };

  int r15 = lane & 15, g = lane >> 4;
  int s0 = g ^ (r15 & 7);
  const int o0 = s0 * 8, o1 = (s0 ^ 4) * 8;
  const int paBase = (wr * (BM / 2) + r15) * 64;
  const int pbBase = (wc * 64 + r15) * 64;

  int nk = kchunk >> 6;
  stage(0, 0);
  __syncthreads();
  for (int t = 0; t < nk; ++t){
    int cur = t & 1;
    if (t + 1 < nk) stage(cur ^ 1, (t + 1) << 6);
    const u16* pa = sA + cur * ASZ;
    const u16* pb = sB + cur * BSZ;
    bf16x8 af[MFR][2], bfv[4][2];
#pragma unroll
    for (int mi = 0; mi < MFR; ++mi){
      af[mi][0] = *(const bf16x8*)(pa + paBase + mi * 1024 + o0);
      af[mi][1] = *(const bf16x8*)(pa + paBase + mi * 1024 + o1);
    }
#pragma unroll
    for (int ni = 0; ni < 4; ++ni){
      bfv[ni][0] = *(const bf16x8*)(pb + pbBase + ni * 1024 + o0);
      bfv[ni][1] = *(const bf16x8*)(pb + pbBase + ni * 1024 + o1);
    }
#pragma unroll
    for (int kk = 0; kk < 2; ++kk)
#pragma unroll
      for (int mi = 0; mi < MFR; ++mi)
#pragma unroll
        for (int ni = 0; ni < 4; ++ni)
          acc[mi][ni] = __builtin_amdgcn_mfma_f32_16x16x32_bf16(af[mi][kk], bfv[ni][kk], acc[mi][ni], 0, 0, 0);
    __syncthreads();
  }

  int colf = lane & 15, rowf = (lane >> 4) << 2;
  if (Cpart){
    u16* dst = Cpart + (size_t)z * M * N;
#pragma unroll
    for (int ni = 0; ni < 4; ++ni){
      int cg = n0 + (wc << 6) + ni * 16 + colf;
#pragma unroll
      for (int mi = 0; mi < MFR; ++mi){
        int rg = m0 + wr * (BM / 2) + mi * 16 + rowf;
#pragma unroll
        for (int r = 0; r < 4; ++r)
          dst[(size_t)(rg + r) * N + cg] = f2bf(acc[mi][ni][r]);
      }
    }
  } else {
#pragma unroll
    for (int ni = 0; ni < 4; ++ni){
      int cg = n0 + (wc << 6) + ni * 16 + colf;
      float bv = bias ? bias[cg] : 0.0f;
#pragma unroll
      for (int mi = 0; mi < MFR; ++mi){
        int rg = m0 + wr * (BM / 2) + mi * 16 + rowf;
#pragma unroll
        for (int r = 0; r < 4; ++r){
          float val = acc[mi][ni][r] + bv;
          if (relu) val = fmaxf(val, 0.0f);
          size_t o = (size_t)(rg + r) * N + cg;
          if (C)   C[o]   = val;
          if (Cbf) (Cbf + (size_t)z * zC)[o] = f2bf(val);
        }
      }
    }
  }
}

// ---------------- V transpose into vtbf [bn][d][jdst0 + j] ----------------
__global__ __launch_bounds__(256) void vtrans(const u16* __restrict__ src, int sstride, int co,
                                              u16* __restrict__ dst, int jdst0,
                                              size_t zsrc, size_t zdst){
  __shared__ u16 s[64 * 68];
  int jt = blockIdx.x, bnp = blockIdx.y;
  int b = bnp >> 4, n = bnp & 15;
  int t = threadIdx.x;
  const u16* sp = src + blockIdx.z * zsrc;
  u16* dp = dst + blockIdx.z * zdst;
  int j0l = jt << 6;
#pragma unroll
  for (int rr = 0; rr < 16; ++rr){
    int idx = rr * 256 + t;
    int jl = idx >> 6, dd = idx & 63;
    s[jl * 68 + dd] = sp[(size_t)((j0l + jl) * 4 + b) * sstride + co + n * 128 + 64 + dd];
  }
  __syncthreads();
#pragma unroll
  for (int ww = 0; ww < 16; ++ww){
    int idx = ww * 256 + t;
    int dd = idx >> 6, jl = idx & 63;
    dp[((size_t)(bnp * 64 + dd) << 10) + jdst0 + j0l + jl] = s[jl * 68 + dd];
  }
}

// ---------------- MFMA flash attention, KV-split, LDS-staged K/V tiles ----------------
// Block = 64 q-rows x one (b,n); all 4 waves share the K/V tile -> stage once, double-buffered.
// Coalesced gload16 staging (was: 64-line gathers per operand load). row&7 slot swizzle.
__global__ __launch_bounds__(256) void attn_mfma_split(
    const u16* __restrict__ qkv, const u16* __restrict__ kvm,
    const u16* __restrict__ vtbf, float* __restrict__ obuf, float* __restrict__ mlbuf)
{
  __shared__ __align__(16) u16 sK[2][64 * 64];
  __shared__ __align__(16) u16 sV[2][64 * 64];
  int tid = threadIdx.x, lane = tid & 63, wid = tid >> 6;
  int g = lane >> 4, t = lane & 15;
  int qt = blockIdx.x, bnp = blockIdx.y, half = blockIdx.z;
  int b = bnp >> 4, n = bnp & 15;
  int i0 = qt * 64 + wid * 16;
  int i = i0 + t;

  union Cvt { u32x4 u; bf16x8 v; };

  bf16x8 qfrag[2];
#pragma unroll
  for (int ks = 0; ks < 2; ++ks)
    qfrag[ks] = *(const bf16x8*)(qkv + (size_t)(i * 4 + b) * 3072 + n * 64 + ks * 32 + g * 8);

  f32x4 oacc[4];
#pragma unroll
  for (int df = 0; df < 4; ++df) oacc[df] = (f32x4)(0.0f);
  float mrun = -1e30f, lrun = 0.0f;

  const u16* kb2; size_t kst; int joff, kt0, kt1;
  if (half == 0){ kb2 = kvm + n * 128;        kst = 2048; joff = 0;   kt0 = 0; kt1 = 8; }
  else          { kb2 = qkv + 1024 + n * 128; kst = 3072; joff = 512; kt0 = 8; kt1 = qt + 9; }
  const u16* vb2 = vtbf + ((size_t)bnp << 16);   // rows d, stride 1024

  int srow = tid >> 3;                    // 0..31
  int gsl = ((tid & 7) ^ (srow & 7)) << 3;

  auto stageKV = [&](int buf, int kt){
    int j0 = kt << 6;
#pragma unroll
    for (int p = 0; p < 2; ++p){
      int jl = srow + p * 32;
      gload16(kb2 + (size_t)((j0 + jl - joff) * 4 + b) * kst + gsl, (void*)&sK[buf][p * 2048 + tid * 8]);
    }
#pragma unroll
    for (int p = 0; p < 2; ++p){
      int dl = srow + p * 32;
      gload16(vb2 + ((size_t)dl << 10) + j0 + gsl, (void*)&sV[buf][p * 2048 + tid * 8]);
    }
  };

  stageKV(0, kt0);
  __syncthreads();
  for (int kt = kt0; kt < kt1; ++kt){
    int cur = (kt - kt0) & 1;
    if (kt + 1 < kt1) stageKV(cur ^ 1, kt + 1);
    int j0 = kt << 6;
    f32x4 sacc[4];
#pragma unroll
    for (int jf = 0; jf < 4; ++jf) sacc[jf] = (f32x4)(0.0f);
#pragma unroll
    for (int ks = 0; ks < 2; ++ks){
      int sl = ((ks * 4 + g) ^ (t & 7)) * 8;
#pragma unroll
      for (int jf = 0; jf < 4; ++jf){
        bf16x8 kf = *(const bf16x8*)(&sK[cur][(jf * 16 + t) * 64 + sl]);
        sacc[jf] = __builtin_amdgcn_mfma_f32_16x16x32_bf16(kf, qfrag[ks], sacc[jf], 0, 0, 0);
      }
    }
    bool part = (half == 1) && (j0 + 63 > i0 + 512);
    float ps[4][4];
    float tmax = -1e30f;
#pragma unroll
    for (int jf = 0; jf < 4; ++jf)
#pragma unroll
      for (int r = 0; r < 4; ++r){
        float s = sacc[jf][r] * 0.125f;
        if (part && (j0 + jf * 16 + g * 4 + r > i + 512)) s = -1e30f;
        ps[jf][r] = s;
        tmax = fmaxf(tmax, s);
      }
    tmax = fmaxf(tmax, __shfl_xor(tmax, 16));
    tmax = fmaxf(tmax, __shfl_xor(tmax, 32));
    float mnew = fmaxf(mrun, tmax);
    float sc = __expf(mrun - mnew);
    mrun = mnew;
    lrun *= sc;
    u32 pk0[2], pk1[2], pk2[2], pk3[2];
    {
      float e0, e1, e2, e3;
#define DO_JF(PK, JF) \
      e0 = __expf(ps[JF][0] - mnew); e1 = __expf(ps[JF][1] - mnew); \
      e2 = __expf(ps[JF][2] - mnew); e3 = __expf(ps[JF][3] - mnew); \
      lrun += (e0 + e1) + (e2 + e3); \
      PK[0] = pack2bf(e0, e1); PK[1] = pack2bf(e2, e3);
      DO_JF(pk0, 0) DO_JF(pk1, 1) DO_JF(pk2, 2) DO_JF(pk3, 3)
#undef DO_JF
    }
#pragma unroll
    for (int df = 0; df < 4; ++df)
#pragma unroll
      for (int r = 0; r < 4; ++r) oacc[df][r] *= sc;

    int srcA = t + 16 * ((2 * g) & 3);
    int srcB = t + 16 * ((2 * g + 1) & 3);
    bool ghi = (g >= 2);
#pragma unroll
    for (int ks = 0; ks < 2; ++ks){
      u32 w0a, w1a, w2a, w3a, w0b, w1b, w2b, w3b;
      if (ks == 0){
        w0a = __shfl((int)pk0[0], srcA); w1a = __shfl((int)pk0[1], srcA);
        w2a = __shfl((int)pk0[0], srcB); w3a = __shfl((int)pk0[1], srcB);
        w0b = __shfl((int)pk1[0], srcA); w1b = __shfl((int)pk1[1], srcA);
        w2b = __shfl((int)pk1[0], srcB); w3b = __shfl((int)pk1[1], srcB);
      } else {
        w0a = __shfl((int)pk2[0], srcA); w1a = __shfl((int)pk2[1], srcA);
        w2a = __shfl((int)pk2[0], srcB); w3a = __shfl((int)pk2[1], srcB);
        w0b = __shfl((int)pk3[0], srcA); w1b = __shfl((int)pk3[1], srcA);
        w2b = __shfl((int)pk3[0], srcB); w3b = __shfl((int)pk3[1], srcB);
      }
      Cvt c;
      c.u[0] = ghi ? w0b : w0a;
      c.u[1] = ghi ? w1b : w1a;
      c.u[2] = ghi ? w2b : w2a;
      c.u[3] = ghi ? w3b : w3a;
      bf16x8 pf = c.v;
      int sl = ((ks * 4 + g) ^ (t & 7)) * 8;
#pragma unroll
      for (int df = 0; df < 4; ++df){
        bf16x8 vf = *(const bf16x8*)(&sV[cur][(df * 16 + t) * 64 + sl]);
        oacc[df] = __builtin_amdgcn_mfma_f32_16x16x32_bf16(vf, pf, oacc[df], 0, 0, 0);
      }
    }
    __syncthreads();
  }
  lrun += __shfl_xor(lrun, 16);
  lrun += __shfl_xor(lrun, 32);

  float* orow = obuf + ((size_t)(half * 2048 + i * 4 + b) << 10) + n * 64;
#pragma unroll
  for (int df = 0; df < 4; ++df){
#pragma unroll
    for (int h = 0; h < 2; ++h){
      orow[df * 16 + g * 4 + 2 * h]     = oacc[df][2 * h];
      orow[df * 16 + g * 4 + 2 * h + 1] = oacc[df][2 * h + 1];
    }
  }
  if (g == 0){
    float* ml = mlbuf + (((size_t)(half * 2048 + i * 4 + b)) * 16 + n) * 2;
    ml[0] = mrun; ml[1] = lrun;
  }
}

// ---------------- merge the two KV halves (log-sum-exp weighting) ----------------
__global__ __launch_bounds__(256) void attn_merge(const float* __restrict__ obuf,
                                                  const float* __restrict__ mlbuf,
                                                  u16* __restrict__ attnbf){
  int r = blockIdx.x, tid = threadIdx.x;
  int d0 = tid * 4, n = tid >> 4;
  const float* ml0 = mlbuf + ((size_t)r * 16 + n) * 2;
  const float* ml1 = mlbuf + ((size_t)(2048 + r) * 16 + n) * 2;
  float m0 = ml0[0], l0 = ml0[1], m1 = ml1[0], l1 = ml1[1];
  float M = fmaxf(m0, m1);
  float w0 = __expf(m0 - M), w1 = __expf(m1 - M);
  float inv = 1.0f / (w0 * l0 + w1 * l1);
  f32x4 o0 = *(const f32x4*)(obuf + ((size_t)r << 10) + d0);
  f32x4 o1 = *(const f32x4*)(obuf + ((size_t)(2048 + r) << 10) + d0);
  u16x4 o;
#pragma unroll
  for (int j = 0; j < 4; ++j) o[j] = f2bf((w0 * o0[j] + w1 * o1[j]) * inv);
  *(u16x4*)(attnbf + ((size_t)r << 10) + d0) = o;
}

// ---------------- residual + (bf16 split-K partial sum) + bias + layernorm ----------------
__global__ __launch_bounds__(256) void ln_k(const float* __restrict__ res, const u16* __restrict__ parts,
                                            size_t pstride, int np, const float* __restrict__ bias,
                                            const float* __restrict__ g, const float* __restrict__ bta,
                                            float* hout, u16* __restrict__ hbf)
{
  int row = blockIdx.x, tid = threadIdx.x;
  int d0 = tid << 2;
  size_t ro = (size_t)row << 10;
  f32x4 v = *(const f32x4*)(res + ro + d0);
  if (bias){
    f32x4 bv = *(const f32x4*)(bias + d0);
#pragma unroll
    for (int j = 0; j < 4; ++j) v[j] += bv[j];
  }
  for (int p = 0; p < np; ++p){
    u16x4 pv = *(const u16x4*)(parts + p * pstride + ro + d0);
#pragma unroll
    for (int j = 0; j < 4; ++j) v[j] += bf2f(pv[j]);
  }
  float s = (v[0] + v[1]) + (v[2] + v[3]);
  float s2 = (v[0] * v[0] + v[1] * v[1]) + (v[2] * v[2] + v[3] * v[3]);
#pragma unroll
  for (int off = 32; off; off >>= 1){ s += __shfl_xor(s, off); s2 += __shfl_xor(s2, off); }
  __shared__ float ps[8];
  int wid = tid >> 6, lane = tid & 63;
  if (lane == 0){ ps[wid] = s; ps[wid + 4] = s2; }
  __syncthreads();
  s  = ps[0] + ps[1] + ps[2] + ps[3];
  s2 = ps[4] + ps[5] + ps[6] + ps[7];
  float mu = s * 0.0009765625f;
  float var = s2 * 0.0009765625f - mu * mu;
  float rstd = rsqrtf(var + 1e-5f);
  f32x4 gv = *(const f32x4*)(g + d0);
  f32x4 bt = *(const f32x4*)(bta + d0);
  f32x4 ho;
  u16x4 hb;
#pragma unroll
  for (int j = 0; j < 4; ++j){
    float tv = (v[j] - mu) * rstd * gv[j] + bt[j];
    ho[j] = tv; hb[j] = f2bf(tv);
  }
  *(f32x4*)(hout + ro + d0) = ho;
  *(u16x4*)(hbf + ro + d0) = hb;
}

__global__ __launch_bounds__(256) void copy_f32(const f32x4* __restrict__ src, f32x4* __restrict__ dst){
  size_t i = (size_t)blockIdx.x * 256 + threadIdx.x;
  dst[i] = src[i];
}

extern "C" void kernel_launch(void* const* d_in, const int* in_sizes, int n_in,
                              void* d_out, int out_size, void* d_ws, size_t ws_size,
                              hipStream_t stream)
{
  const int*   data = (const int*)  d_in[0];
  const float* mems = (const float*)d_in[1];
  const float* emb  = (const float*)d_in[2];
  const float* Wq   = (const float*)d_in[3];
  const float* Wkv  = (const float*)d_in[4];
  const float* Wo   = (const float*)d_in[5];
  const float* ln1g = (const float*)d_in[6];
  const float* ln1b = (const float*)d_in[7];
  const float* W1   = (const float*)d_in[8];
  const float* b1   = (const float*)d_in[9];
  const float* W2   = (const float*)d_in[10];
  const float* b2   = (const float*)d_in[11];
  const float* ln2g = (const float*)d_in[12];
  const float* ln2b = (const float*)d_in[13];
  float* out = (float*)d_out;

  char* ws = (char*)d_ws;
  size_t off = 0;
  auto alloc = [&](size_t bytes) -> char* {
    char* p = ws + off;
    off = (off + bytes + 255) & ~(size_t)255;
    return p;
  };

  // fused transposed QKV weights: [l][3072][1024] (rows 0..1023 = Wq^T, 1024..3071 = Wkv^T)
  u16*   wqkv_bf = (u16*) alloc((size_t)6 * 3072 * 1024 * 2);
  u16*   wo_bf   = (u16*) alloc((size_t)6 * 1024 * 1024 * 2);
  u16*   w1_bf   = (u16*) alloc((size_t)6 * 4096 * 1024 * 2);
  u16*   w2_bf   = (u16*) alloc((size_t)6 * 1024 * 4096 * 2);
  u16*   memsbf  = (u16*) alloc((size_t)6 * 2048 * 1024 * 2);
  u16*   kvmem   = (u16*) alloc((size_t)6 * 2048 * 2048 * 2);   // per-layer mems-KV
  u16*   vtbf    = (u16*) alloc((size_t)6 * 64 * 64 * 1024 * 2);
  float* h       = (float*)alloc((size_t)2048 * 1024 * 4);
  u16*   hbf     = (u16*) alloc((size_t)2048 * 1024 * 2);
  u16*   qkv     = (u16*) alloc((size_t)2048 * 3072 * 2);
  u16*   attnbf  = (u16*) alloc((size_t)2048 * 1024 * 2);
  u16*   f1bf    = (u16*) alloc((size_t)2048 * 4096 * 2);
  float* pbuf    = (float*)alloc((size_t)4 * 2048 * 1024 * 4);  // attn f32 halves / bf16 partials
  float* mlbuf   = (float*)alloc((size_t)2 * 2048 * 16 * 2 * 4);
  u16*   pbf     = (u16*)pbuf;
  const size_t PS = (size_t)2048 * 1024;
  const size_t VTL = (size_t)64 * 64 * 1024;

  // ---- layer-independent preamble (full-chip parallel) ----
  conv_bf16_t<<<dim3(16, 16, 6), 256, 0, stream>>>(Wq,  wqkv_bf, 1024, 1024, (size_t)3072 * 1024, 0);
  conv_bf16_t<<<dim3(32, 16, 6), 256, 0, stream>>>(Wkv, wqkv_bf, 1024, 2048, (size_t)3072 * 1024, 1024);
  conv_bf16_t<<<dim3(16, 16, 6), 256, 0, stream>>>(Wo,  wo_bf,   1024, 1024, (size_t)1024 * 1024, 0);
  conv_bf16_t<<<dim3(64, 16, 6), 256, 0, stream>>>(W1,  w1_bf,   1024, 4096, (size_t)4096 * 1024, 0);
  conv_bf16_t<<<dim3(16, 64, 6), 256, 0, stream>>>(W2,  w2_bf,   4096, 1024, (size_t)4096 * 1024, 0);
  conv_bf16<<<12288, 256, 0, stream>>>(mems, memsbf);
  embed_k<<<8192, 256, 0, stream>>>(data, emb, h, hbf);
  // batched mems-KV GEMM for all 6 layers: kvmem[l] = memsbf[l] @ Wkv[l]
  gemm_bt<64><<<dim3(16, 32, 6), 256, 0, stream>>>(memsbf, wqkv_bf + (size_t)1024 * 1024, nullptr,
      nullptr, kvmem, nullptr, 2048, 2048, 1024, 1024, 0,
      (size_t)2048 * 1024, (size_t)3072 * 1024, (size_t)2048 * 2048);
  // mems-V transpose for all layers (j < 512)
  vtrans<<<dim3(8, 64, 6), 256, 0, stream>>>(kvmem, 2048, 0, vtbf, 0, (size_t)2048 * 2048, VTL);

  for (int l = 0; l < 6; ++l){
    u16* kvm_l = kvmem + (size_t)l * 2048 * 2048;
    u16* vt_l  = vtbf + (size_t)l * VTL;
    // fused Q/KV(h) GEMM: qkv[2048][3072]
    gemm_bt<64><<<dim3(24, 32), 256, 0, stream>>>(hbf, wqkv_bf + (size_t)l * 3072 * 1024, nullptr,
        nullptr, qkv, nullptr, 2048, 3072, 1024, 1024, 0, 0, 0, 0);
    // h-part V transpose (j >= 512)
    vtrans<<<dim3(8, 64), 256, 0, stream>>>(qkv, 3072, 1024, vt_l, 512, 0, 0);
    // attention: 2 KV-halves in parallel (LDS-staged tiles), then merge
    attn_mfma_split<<<dim3(8, 64, 2), 256, 0, stream>>>(qkv, kvm_l, vt_l, pbuf, mlbuf);
    attn_merge<<<2048, 256, 0, stream>>>(pbuf, mlbuf, attnbf);
    // Wo: split-K x2 -> bf16 partials, summed inside ln1
    gemm_bt<64><<<dim3(8, 32, 2), 256, 0, stream>>>(attnbf, wo_bf + (size_t)l * 1024 * 1024, nullptr,
        nullptr, nullptr, pbf, 2048, 1024, 1024, 512, 0, 0, 0, 0);
    ln_k<<<2048, 256, 0, stream>>>(h, pbf, PS, 2, nullptr, ln1g + l * 1024, ln1b + l * 1024, h, hbf);
    // W1 + bias + relu
    gemm_bt<64><<<dim3(32, 32), 256, 0, stream>>>(hbf, w1_bf + (size_t)l * 4096 * 1024,
        b1 + (size_t)l * 4096, nullptr, f1bf, nullptr, 2048, 4096, 1024, 1024, 1, 0, 0, 0);
    // W2: split-K x4 -> bf16 partials, summed (+b2) inside ln2
    gemm_bt<64><<<dim3(8, 32, 4), 256, 0, stream>>>(f1bf, w2_bf + (size_t)l * 4096 * 1024, nullptr,
        nullptr, nullptr, pbf, 2048, 1024, 4096, 1024, 0, 0, 0, 0);
    ln_k<<<2048, 256, 0, stream>>>(h, pbf, PS, 4, b2 + l * 1024, ln2g + l * 1024, ln2b + l * 1024, h, hbf);
  }
  copy_f32<<<2048, 256, 0, stream>>>((const f32x4*)h, (f32x4*)out);
}

// Round 11
// 1189.216 us; speedup vs baseline: 1.3125x; 1.0251x over previous
//
#include <hip/hip_runtime.h>

typedef unsigned short u16;
typedef unsigned int u32;
typedef __bf16 bf16x8 __attribute__((ext_vector_type(8)));
typedef float f32x4 __attribute__((ext_vector_type(4)));
typedef u16 u16x8 __attribute__((ext_vector_type(8)));
typedef u16 u16x4 __attribute__((ext_vector_type(4)));
typedef u32 u32x4 __attribute__((ext_vector_type(4)));

__device__ __forceinline__ u16 f2bf(float f){
  unsigned u = __float_as_uint(f);
  u += 0x7FFFu + ((u >> 16) & 1u);   // RNE
  return (u16)(u >> 16);
}
__device__ __forceinline__ float bf2f(u16 u){
  return __uint_as_float((u32)u << 16);
}
__device__ __forceinline__ u32 pack2bf(float a, float b){
  return (u32)f2bf(a) | ((u32)f2bf(b) << 16);
}
__device__ __forceinline__ void gload16(const void* g, void* l){
  __builtin_amdgcn_global_load_lds(
      (const __attribute__((address_space(1))) void*)g,
      (__attribute__((address_space(3))) void*)l, 16, 0, 0);
}

// ---------------- weight f32 [K][N] -> bf16 [drow0+N][K] (transposing convert) ----------------
__global__ __launch_bounds__(256) void conv_bf16_t(const float* __restrict__ src, u16* __restrict__ dst,
                                                   int K, int N, size_t dls, int drow0){
  __shared__ u16 s[64 * 68];
  size_t lo = (size_t)blockIdx.z * K * N;
  int n0 = blockIdx.x << 6, k0 = blockIdx.y << 6;
  int t = threadIdx.x;
#pragma unroll
  for (int p = 0; p < 4; ++p){
    int idx = p * 1024 + t * 4;
    int kl = idx >> 6, nl = idx & 63;
    f32x4 v = *(const f32x4*)(src + lo + (size_t)(k0 + kl) * N + n0 + nl);
#pragma unroll
    for (int j = 0; j < 4; ++j) s[(nl + j) * 68 + kl] = f2bf(v[j]);
  }
  __syncthreads();
  u16* db = dst + blockIdx.z * dls;
#pragma unroll
  for (int p = 0; p < 4; ++p){
    int idx = p * 1024 + t * 4;
    int nl = idx >> 6, kl = idx & 63;
    u16x4 o;
#pragma unroll
    for (int j = 0; j < 4; ++j) o[j] = s[nl * 68 + kl + j];
    *(u16x4*)(db + (size_t)(drow0 + n0 + nl) * K + k0 + kl) = o;
  }
}

// ---------------- plain f32 -> bf16 ----------------
__global__ __launch_bounds__(256) void conv_bf16(const float* __restrict__ src, u16* __restrict__ dst){
  size_t i = ((size_t)blockIdx.x * 256 + threadIdx.x) * 4;
  f32x4 v = *(const f32x4*)(src + i);
  u16x4 o;
#pragma unroll
  for (int j = 0; j < 4; ++j) o[j] = f2bf(v[j]);
  *(u16x4*)(dst + i) = o;
}

// ---------------- embedding + positional encoding ----------------
__global__ __launch_bounds__(256) void embed_k(const int* __restrict__ data, const float* __restrict__ emb,
                                               float* __restrict__ h, u16* __restrict__ hbf){
  int idx = blockIdx.x * 256 + threadIdx.x;       // 0 .. 2M-1
  int r = idx >> 10, d = idx & 1023;              // r = i*4+b
  int i = r >> 2;
  int e = data[r];
  float val = emb[(size_t)e * 1024 + d] * 32.0f;  // sqrt(1024)
  float pos = (float)(511 - i);
  int t = d & 511;
  float freq = powf(10000.0f, -(float)t * (1.0f / 512.0f));
  float ang = pos * freq;
  val += (d < 512) ? sinf(ang) : cosf(ang);
  h[idx] = val;
  hbf[idx] = f2bf(val);
}

// ---------------- bf16 MFMA GEMM: C = A[M,K] @ Bt[N,K]^T ----------------
// BK=64, 2-buffer R5 schedule, row&7 slot swizzle (both-sides). Cpart = bf16 partials.
// BM=128: 2:1 MFMA:ds_read density, 64KB LDS (2 blocks/CU). BM=64: 48KB, 3 blocks/CU.
// blockIdx.z = K-chunk (if Cpart) or batch (zA/zB/zC strides).
template<int BM>
__global__ __launch_bounds__(256) void gemm_bt(
    const u16* __restrict__ A, const u16* __restrict__ Bt,
    const float* __restrict__ bias, float* __restrict__ C, u16* __restrict__ Cbf,
    u16* __restrict__ Cpart, int M, int N, int K, int kchunk, int relu,
    size_t zA, size_t zB, size_t zC)
{
  constexpr int MFR = BM / 32;            // A frags per wave
  constexpr int ASZ = BM * 64, BSZ = 128 * 64;   // elements per buffer
  __shared__ __align__(16) u16 sA[2 * ASZ];
  __shared__ __align__(16) u16 sB[2 * BSZ];
  int tid = threadIdx.x, lane = tid & 63;
  int wr = (tid >> 7) & 1, wc = (tid >> 6) & 1;
  int m0 = blockIdx.y * BM, n0 = blockIdx.x << 7;
  int z = blockIdx.z;
  int kbeg = Cpart ? z * kchunk : 0;

  const u16* Ap = A + (size_t)z * zA;
  const u16* Bp = Bt + (size_t)z * zB;

  f32x4 acc[MFR][4];
#pragma unroll
  for (int i = 0; i < MFR; ++i)
#pragma unroll
    for (int j = 0; j < 4; ++j) acc[i][j] = (f32x4)(0.0f);

  int srow8 = tid >> 3;                   // 0..31
  int gslot8 = ((tid & 7) ^ (srow8 & 7)) << 3;
  const u16* Ab = Ap + (size_t)(m0 + srow8) * K + kbeg + gslot8;
  const u16* Bb = Bp + (size_t)(n0 + srow8) * K + kbeg + gslot8;
  const size_t rstep32 = (size_t)K << 5;  // 32 rows

  auto stage = [&](int buf, int k0){
#pragma unroll
    for (int p = 0; p < BM / 32; ++p)
      gload16(Ab + p * rstep32 + k0, (void*)&sA[buf * ASZ + p * 2048 + tid * 8]);
#pragma unroll
    for (int p = 0; p < 4; ++p)
      gload16(Bb + p * rstep32 + k0, (void*)&sB[buf * BSZ + p * 2048 + tid * 8]);
  };

  int r15 = lane & 15, g = lane >> 4;
  int s0 = g ^ (r15 & 7);
  const int o0 = s0 * 8, o1 = (s0 ^ 4) * 8;
  const int paBase = (wr * (BM / 2) + r15) * 64;
  const int pbBase = (wc * 64 + r15) * 64;

  int nk = kchunk >> 6;
  stage(0, 0);
  __syncthreads();
  for (int t = 0; t < nk; ++t){
    int cur = t & 1;
    if (t + 1 < nk) stage(cur ^ 1, (t + 1) << 6);
    const u16* pa = sA + cur * ASZ;
    const u16* pb = sB + cur * BSZ;
    bf16x8 af[MFR][2], bfv[4][2];
#pragma unroll
    for (int mi = 0; mi < MFR; ++mi){
      af[mi][0] = *(const bf16x8*)(pa + paBase + mi * 1024 + o0);
      af[mi][1] = *(const bf16x8*)(pa + paBase + mi * 1024 + o1);
    }
#pragma unroll
    for (int ni = 0; ni < 4; ++ni){
      bfv[ni][0] = *(const bf16x8*)(pb + pbBase + ni * 1024 + o0);
      bfv[ni][1] = *(const bf16x8*)(pb + pbBase + ni * 1024 + o1);
    }
#pragma unroll
    for (int kk = 0; kk < 2; ++kk)
#pragma unroll
      for (int mi = 0; mi < MFR; ++mi)
#pragma unroll
        for (int ni = 0; ni < 4; ++ni)
          acc[mi][ni] = __builtin_amdgcn_mfma_f32_16x16x32_bf16(af[mi][kk], bfv[ni][kk], acc[mi][ni], 0, 0, 0);
    __syncthreads();
  }

  int colf = lane & 15, rowf = (lane >> 4) << 2;
  if (Cpart){
    u16* dst = Cpart + (size_t)z * M * N;
#pragma unroll
    for (int ni = 0; ni < 4; ++ni){
      int cg = n0 + (wc << 6) + ni * 16 + colf;
#pragma unroll
      for (int mi = 0; mi < MFR; ++mi){
        int rg = m0 + wr * (BM / 2) + mi * 16 + rowf;
#pragma unroll
        for (int r = 0; r < 4; ++r)
          dst[(size_t)(rg + r) * N + cg] = f2bf(acc[mi][ni][r]);
      }
    }
  } else {
#pragma unroll
    for (int ni = 0; ni < 4; ++ni){
      int cg = n0 + (wc << 6) + ni * 16 + colf;
      float bv = bias ? bias[cg] : 0.0f;
#pragma unroll
      for (int mi = 0; mi < MFR; ++mi){
        int rg = m0 + wr * (BM / 2) + mi * 16 + rowf;
#pragma unroll
        for (int r = 0; r < 4; ++r){
          float val = acc[mi][ni][r] + bv;
          if (relu) val = fmaxf(val, 0.0f);
          size_t o = (size_t)(rg + r) * N + cg;
          if (C)   C[o]   = val;
          if (Cbf) (Cbf + (size_t)z * zC)[o] = f2bf(val);
        }
      }
    }
  }
}

// ---------------- V transpose into vtbf [bn][d][jdst0 + j] ----------------
__global__ __launch_bounds__(256) void vtrans(const u16* __restrict__ src, int sstride, int co,
                                              u16* __restrict__ dst, int jdst0,
                                              size_t zsrc, size_t zdst){
  __shared__ u16 s[64 * 68];
  int jt = blockIdx.x, bnp = blockIdx.y;
  int b = bnp >> 4, n = bnp & 15;
  int t = threadIdx.x;
  const u16* sp = src + blockIdx.z * zsrc;
  u16* dp = dst + blockIdx.z * zdst;
  int j0l = jt << 6;
#pragma unroll
  for (int rr = 0; rr < 16; ++rr){
    int idx = rr * 256 + t;
    int jl = idx >> 6, dd = idx & 63;
    s[jl * 68 + dd] = sp[(size_t)((j0l + jl) * 4 + b) * sstride + co + n * 128 + 64 + dd];
  }
  __syncthreads();
#pragma unroll
  for (int ww = 0; ww < 16; ++ww){
    int idx = ww * 256 + t;
    int dd = idx >> 6, jl = idx & 63;
    dp[((size_t)(bnp * 64 + dd) << 10) + jdst0 + j0l + jl] = s[jl * 68 + dd];
  }
}

// ---------------- MFMA flash attention, KV-split, LDS-staged K/V tiles ----------------
// Block = 64 q-rows x one (b,n); all 4 waves share the K/V tile -> stage once, double-buffered.
// O-halves written as bf16 (merge rescales; ~0.4% rel error, negligible).
__global__ __launch_bounds__(256) void attn_mfma_split(
    const u16* __restrict__ qkv, const u16* __restrict__ kvm,
    const u16* __restrict__ vtbf, u16* __restrict__ obuf, float* __restrict__ mlbuf)
{
  __shared__ __align__(16) u16 sK[2][64 * 64];
  __shared__ __align__(16) u16 sV[2][64 * 64];
  int tid = threadIdx.x, lane = tid & 63, wid = tid >> 6;
  int g = lane >> 4, t = lane & 15;
  int qt = blockIdx.x, bnp = blockIdx.y, half = blockIdx.z;
  int b = bnp >> 4, n = bnp & 15;
  int i0 = qt * 64 + wid * 16;
  int i = i0 + t;

  union Cvt { u32x4 u; bf16x8 v; };

  bf16x8 qfrag[2];
#pragma unroll
  for (int ks = 0; ks < 2; ++ks)
    qfrag[ks] = *(const bf16x8*)(qkv + (size_t)(i * 4 + b) * 3072 + n * 64 + ks * 32 + g * 8);

  f32x4 oacc[4];
#pragma unroll
  for (int df = 0; df < 4; ++df) oacc[df] = (f32x4)(0.0f);
  float mrun = -1e30f, lrun = 0.0f;

  const u16* kb2; size_t kst; int joff, kt0, kt1;
  if (half == 0){ kb2 = kvm + n * 128;        kst = 2048; joff = 0;   kt0 = 0; kt1 = 8; }
  else          { kb2 = qkv + 1024 + n * 128; kst = 3072; joff = 512; kt0 = 8; kt1 = qt + 9; }
  const u16* vb2 = vtbf + ((size_t)bnp << 16);   // rows d, stride 1024

  int srow = tid >> 3;                    // 0..31
  int gsl = ((tid & 7) ^ (srow & 7)) << 3;

  auto stageKV = [&](int buf, int kt){
    int j0 = kt << 6;
#pragma unroll
    for (int p = 0; p < 2; ++p){
      int jl = srow + p * 32;
      gload16(kb2 + (size_t)((j0 + jl - joff) * 4 + b) * kst + gsl, (void*)&sK[buf][p * 2048 + tid * 8]);
    }
#pragma unroll
    for (int p = 0; p < 2; ++p){
      int dl = srow + p * 32;
      gload16(vb2 + ((size_t)dl << 10) + j0 + gsl, (void*)&sV[buf][p * 2048 + tid * 8]);
    }
  };

  stageKV(0, kt0);
  __syncthreads();
  for (int kt = kt0; kt < kt1; ++kt){
    int cur = (kt - kt0) & 1;
    if (kt + 1 < kt1) stageKV(cur ^ 1, kt + 1);
    int j0 = kt << 6;
    f32x4 sacc[4];
#pragma unroll
    for (int jf = 0; jf < 4; ++jf) sacc[jf] = (f32x4)(0.0f);
#pragma unroll
    for (int ks = 0; ks < 2; ++ks){
      int sl = ((ks * 4 + g) ^ (t & 7)) * 8;
#pragma unroll
      for (int jf = 0; jf < 4; ++jf){
        bf16x8 kf = *(const bf16x8*)(&sK[cur][(jf * 16 + t) * 64 + sl]);
        sacc[jf] = __builtin_amdgcn_mfma_f32_16x16x32_bf16(kf, qfrag[ks], sacc[jf], 0, 0, 0);
      }
    }
    bool part = (half == 1) && (j0 + 63 > i0 + 512);
    float ps[4][4];
    float tmax = -1e30f;
#pragma unroll
    for (int jf = 0; jf < 4; ++jf)
#pragma unroll
      for (int r = 0; r < 4; ++r){
        float s = sacc[jf][r] * 0.125f;
        if (part && (j0 + jf * 16 + g * 4 + r > i + 512)) s = -1e30f;
        ps[jf][r] = s;
        tmax = fmaxf(tmax, s);
      }
    tmax = fmaxf(tmax, __shfl_xor(tmax, 16));
    tmax = fmaxf(tmax, __shfl_xor(tmax, 32));
    float mnew = fmaxf(mrun, tmax);
    float sc = __expf(mrun - mnew);
    mrun = mnew;
    lrun *= sc;
    u32 pk0[2], pk1[2], pk2[2], pk3[2];
    {
      float e0, e1, e2, e3;
#define DO_JF(PK, JF) \
      e0 = __expf(ps[JF][0] - mnew); e1 = __expf(ps[JF][1] - mnew); \
      e2 = __expf(ps[JF][2] - mnew); e3 = __expf(ps[JF][3] - mnew); \
      lrun += (e0 + e1) + (e2 + e3); \
      PK[0] = pack2bf(e0, e1); PK[1] = pack2bf(e2, e3);
      DO_JF(pk0, 0) DO_JF(pk1, 1) DO_JF(pk2, 2) DO_JF(pk3, 3)
#undef DO_JF
    }
#pragma unroll
    for (int df = 0; df < 4; ++df)
#pragma unroll
      for (int r = 0; r < 4; ++r) oacc[df][r] *= sc;

    int srcA = t + 16 * ((2 * g) & 3);
    int srcB = t + 16 * ((2 * g + 1) & 3);
    bool ghi = (g >= 2);
#pragma unroll
    for (int ks = 0; ks < 2; ++ks){
      u32 w0a, w1a, w2a, w3a, w0b, w1b, w2b, w3b;
      if (ks == 0){
        w0a = __shfl((int)pk0[0], srcA); w1a = __shfl((int)pk0[1], srcA);
        w2a = __shfl((int)pk0[0], srcB); w3a = __shfl((int)pk0[1], srcB);
        w0b = __shfl((int)pk1[0], srcA); w1b = __shfl((int)pk1[1], srcA);
        w2b = __shfl((int)pk1[0], srcB); w3b = __shfl((int)pk1[1], srcB);
      } else {
        w0a = __shfl((int)pk2[0], srcA); w1a = __shfl((int)pk2[1], srcA);
        w2a = __shfl((int)pk2[0], srcB); w3a = __shfl((int)pk2[1], srcB);
        w0b = __shfl((int)pk3[0], srcA); w1b = __shfl((int)pk3[1], srcA);
        w2b = __shfl((int)pk3[0], srcB); w3b = __shfl((int)pk3[1], srcB);
      }
      Cvt c;
      c.u[0] = ghi ? w0b : w0a;
      c.u[1] = ghi ? w1b : w1a;
      c.u[2] = ghi ? w2b : w2a;
      c.u[3] = ghi ? w3b : w3a;
      bf16x8 pf = c.v;
      int sl = ((ks * 4 + g) ^ (t & 7)) * 8;
#pragma unroll
      for (int df = 0; df < 4; ++df){
        bf16x8 vf = *(const bf16x8*)(&sV[cur][(df * 16 + t) * 64 + sl]);
        oacc[df] = __builtin_amdgcn_mfma_f32_16x16x32_bf16(vf, pf, oacc[df], 0, 0, 0);
      }
    }
    __syncthreads();
  }
  lrun += __shfl_xor(lrun, 16);
  lrun += __shfl_xor(lrun, 32);

  u16* orow = obuf + ((size_t)(half * 2048 + i * 4 + b) << 10) + n * 64;
#pragma unroll
  for (int df = 0; df < 4; ++df){
#pragma unroll
    for (int h = 0; h < 2; ++h){
      *(u32*)(orow + df * 16 + g * 4 + 2 * h) = pack2bf(oacc[df][2 * h], oacc[df][2 * h + 1]);
    }
  }
  if (g == 0){
    float* ml = mlbuf + (((size_t)(half * 2048 + i * 4 + b)) * 16 + n) * 2;
    ml[0] = mrun; ml[1] = lrun;
  }
}

// ---------------- merge the two KV halves (log-sum-exp weighting) ----------------
__global__ __launch_bounds__(256) void attn_merge(const u16* __restrict__ obuf,
                                                  const float* __restrict__ mlbuf,
                                                  u16* __restrict__ attnbf){
  int r = blockIdx.x, tid = threadIdx.x;
  int d0 = tid * 4, n = tid >> 4;
  const float* ml0 = mlbuf + ((size_t)r * 16 + n) * 2;
  const float* ml1 = mlbuf + ((size_t)(2048 + r) * 16 + n) * 2;
  float m0 = ml0[0], l0 = ml0[1], m1 = ml1[0], l1 = ml1[1];
  float M = fmaxf(m0, m1);
  float w0 = __expf(m0 - M), w1 = __expf(m1 - M);
  float inv = 1.0f / (w0 * l0 + w1 * l1);
  u16x4 o0 = *(const u16x4*)(obuf + ((size_t)r << 10) + d0);
  u16x4 o1 = *(const u16x4*)(obuf + ((size_t)(2048 + r) << 10) + d0);
  u16x4 o;
#pragma unroll
  for (int j = 0; j < 4; ++j) o[j] = f2bf((w0 * bf2f(o0[j]) + w1 * bf2f(o1[j])) * inv);
  *(u16x4*)(attnbf + ((size_t)r << 10) + d0) = o;
}

// ---------------- residual + (bf16 split-K partial sum) + bias + layernorm ----------------
__global__ __launch_bounds__(256) void ln_k(const float* __restrict__ res, const u16* __restrict__ parts,
                                            size_t pstride, int np, const float* __restrict__ bias,
                                            const float* __restrict__ g, const float* __restrict__ bta,
                                            float* hout, u16* __restrict__ hbf)
{
  int row = blockIdx.x, tid = threadIdx.x;
  int d0 = tid << 2;
  size_t ro = (size_t)row << 10;
  f32x4 v = *(const f32x4*)(res + ro + d0);
  if (bias){
    f32x4 bv = *(const f32x4*)(bias + d0);
#pragma unroll
    for (int j = 0; j < 4; ++j) v[j] += bv[j];
  }
  for (int p = 0; p < np; ++p){
    u16x4 pv = *(const u16x4*)(parts + p * pstride + ro + d0);
#pragma unroll
    for (int j = 0; j < 4; ++j) v[j] += bf2f(pv[j]);
  }
  float s = (v[0] + v[1]) + (v[2] + v[3]);
  float s2 = (v[0] * v[0] + v[1] * v[1]) + (v[2] * v[2] + v[3] * v[3]);
#pragma unroll
  for (int off = 32; off; off >>= 1){ s += __shfl_xor(s, off); s2 += __shfl_xor(s2, off); }
  __shared__ float ps[8];
  int wid = tid >> 6, lane = tid & 63;
  if (lane == 0){ ps[wid] = s; ps[wid + 4] = s2; }
  __syncthreads();
  s  = ps[0] + ps[1] + ps[2] + ps[3];
  s2 = ps[4] + ps[5] + ps[6] + ps[7];
  float mu = s * 0.0009765625f;
  float var = s2 * 0.0009765625f - mu * mu;
  float rstd = rsqrtf(var + 1e-5f);
  f32x4 gv = *(const f32x4*)(g + d0);
  f32x4 bt = *(const f32x4*)(bta + d0);
  f32x4 ho;
  u16x4 hb;
#pragma unroll
  for (int j = 0; j < 4; ++j){
    float tv = (v[j] - mu) * rstd * gv[j] + bt[j];
    ho[j] = tv; hb[j] = f2bf(tv);
  }
  *(f32x4*)(hout + ro + d0) = ho;
  *(u16x4*)(hbf + ro + d0) = hb;
}

__global__ __launch_bounds__(256) void copy_f32(const f32x4* __restrict__ src, f32x4* __restrict__ dst){
  size_t i = (size_t)blockIdx.x * 256 + threadIdx.x;
  dst[i] = src[i];
}

extern "C" void kernel_launch(void* const* d_in, const int* in_sizes, int n_in,
                              void* d_out, int out_size, void* d_ws, size_t ws_size,
                              hipStream_t stream)
{
  const int*   data = (const int*)  d_in[0];
  const float* mems = (const float*)d_in[1];
  const float* emb  = (const float*)d_in[2];
  const float* Wq   = (const float*)d_in[3];
  const float* Wkv  = (const float*)d_in[4];
  const float* Wo   = (const float*)d_in[5];
  const float* ln1g = (const float*)d_in[6];
  const float* ln1b = (const float*)d_in[7];
  const float* W1   = (const float*)d_in[8];
  const float* b1   = (const float*)d_in[9];
  const float* W2   = (const float*)d_in[10];
  const float* b2   = (const float*)d_in[11];
  const float* ln2g = (const float*)d_in[12];
  const float* ln2b = (const float*)d_in[13];
  float* out = (float*)d_out;

  char* ws = (char*)d_ws;
  size_t off = 0;
  auto alloc = [&](size_t bytes) -> char* {
    char* p = ws + off;
    off = (off + bytes + 255) & ~(size_t)255;
    return p;
  };

  // fused transposed QKV weights: [l][3072][1024] (rows 0..1023 = Wq^T, 1024..3071 = Wkv^T)
  u16*   wqkv_bf = (u16*) alloc((size_t)6 * 3072 * 1024 * 2);
  u16*   wo_bf   = (u16*) alloc((size_t)6 * 1024 * 1024 * 2);
  u16*   w1_bf   = (u16*) alloc((size_t)6 * 4096 * 1024 * 2);
  u16*   w2_bf   = (u16*) alloc((size_t)6 * 1024 * 4096 * 2);
  u16*   memsbf  = (u16*) alloc((size_t)6 * 2048 * 1024 * 2);
  u16*   kvmem   = (u16*) alloc((size_t)6 * 2048 * 2048 * 2);   // per-layer mems-KV
  u16*   vtbf    = (u16*) alloc((size_t)6 * 64 * 64 * 1024 * 2);
  float* h       = (float*)alloc((size_t)2048 * 1024 * 4);
  u16*   hbf     = (u16*) alloc((size_t)2048 * 1024 * 2);
  u16*   qkv     = (u16*) alloc((size_t)2048 * 3072 * 2);
  u16*   attnbf  = (u16*) alloc((size_t)2048 * 1024 * 2);
  u16*   f1bf    = (u16*) alloc((size_t)2048 * 4096 * 2);
  float* pbuf    = (float*)alloc((size_t)4 * 2048 * 1024 * 4);  // attn bf16 halves / bf16 partials
  float* mlbuf   = (float*)alloc((size_t)2 * 2048 * 16 * 2 * 4);
  u16*   pbf     = (u16*)pbuf;
  const size_t PS = (size_t)2048 * 1024;
  const size_t VTL = (size_t)64 * 64 * 1024;

  // ---- layer-independent preamble (full-chip parallel) ----
  conv_bf16_t<<<dim3(16, 16, 6), 256, 0, stream>>>(Wq,  wqkv_bf, 1024, 1024, (size_t)3072 * 1024, 0);
  conv_bf16_t<<<dim3(32, 16, 6), 256, 0, stream>>>(Wkv, wqkv_bf, 1024, 2048, (size_t)3072 * 1024, 1024);
  conv_bf16_t<<<dim3(16, 16, 6), 256, 0, stream>>>(Wo,  wo_bf,   1024, 1024, (size_t)1024 * 1024, 0);
  conv_bf16_t<<<dim3(64, 16, 6), 256, 0, stream>>>(W1,  w1_bf,   1024, 4096, (size_t)4096 * 1024, 0);
  conv_bf16_t<<<dim3(16, 64, 6), 256, 0, stream>>>(W2,  w2_bf,   4096, 1024, (size_t)4096 * 1024, 0);
  conv_bf16<<<12288, 256, 0, stream>>>(mems, memsbf);
  embed_k<<<8192, 256, 0, stream>>>(data, emb, h, hbf);
  // batched mems-KV GEMM for all 6 layers (BM=128): kvmem[l] = memsbf[l] @ Wkv[l]
  gemm_bt<128><<<dim3(16, 16, 6), 256, 0, stream>>>(memsbf, wqkv_bf + (size_t)1024 * 1024, nullptr,
      nullptr, kvmem, nullptr, 2048, 2048, 1024, 1024, 0,
      (size_t)2048 * 1024, (size_t)3072 * 1024, (size_t)2048 * 2048);
  // mems-V transpose for all layers (j < 512)
  vtrans<<<dim3(8, 64, 6), 256, 0, stream>>>(kvmem, 2048, 0, vtbf, 0, (size_t)2048 * 2048, VTL);

  for (int l = 0; l < 6; ++l){
    u16* kvm_l = kvmem + (size_t)l * 2048 * 2048;
    u16* vt_l  = vtbf + (size_t)l * VTL;
    // fused Q/KV(h) GEMM (BM=128): qkv[2048][3072]
    gemm_bt<128><<<dim3(24, 16), 256, 0, stream>>>(hbf, wqkv_bf + (size_t)l * 3072 * 1024, nullptr,
        nullptr, qkv, nullptr, 2048, 3072, 1024, 1024, 0, 0, 0, 0);
    // h-part V transpose (j >= 512)
    vtrans<<<dim3(8, 64), 256, 0, stream>>>(qkv, 3072, 1024, vt_l, 512, 0, 0);
    // attention: 2 KV-halves in parallel (LDS-staged tiles), then merge
    attn_mfma_split<<<dim3(8, 64, 2), 256, 0, stream>>>(qkv, kvm_l, vt_l, (u16*)pbuf, mlbuf);
    attn_merge<<<2048, 256, 0, stream>>>((const u16*)pbuf, mlbuf, attnbf);
    // Wo: split-K x2 -> bf16 partials, summed inside ln1 (BM=64: grid stays 2/CU)
    gemm_bt<64><<<dim3(8, 32, 2), 256, 0, stream>>>(attnbf, wo_bf + (size_t)l * 1024 * 1024, nullptr,
        nullptr, nullptr, pbf, 2048, 1024, 1024, 512, 0, 0, 0, 0);
    ln_k<<<2048, 256, 0, stream>>>(h, pbf, PS, 2, nullptr, ln1g + l * 1024, ln1b + l * 1024, h, hbf);
    // W1 + bias + relu (BM=128)
    gemm_bt<128><<<dim3(32, 16), 256, 0, stream>>>(hbf, w1_bf + (size_t)l * 4096 * 1024,
        b1 + (size_t)l * 4096, nullptr, f1bf, nullptr, 2048, 4096, 1024, 1024, 1, 0, 0, 0);
    // W2: split-K x4 -> bf16 partials, summed (+b2) inside ln2 (BM=64)
    gemm_bt<64><<<dim3(8, 32, 4), 256, 0, stream>>>(f1bf, w2_bf + (size_t)l * 4096 * 1024, nullptr,
        nullptr, nullptr, pbf, 2048, 1024, 4096, 1024, 0, 0, 0, 0);
    ln_k<<<2048, 256, 0, stream>>>(h, pbf, PS, 4, b2 + l * 1024, ln2g + l * 1024, ln2b + l * 1024, h, hbf);
  }
  copy_f32<<<2048, 256, 0, stream>>>((const f32x4*)h, (f32x4*)out);
}

// Round 12
// 1168.626 us; speedup vs baseline: 1.3357x; 1.0176x over previous
//
#include <hip/hip_runtime.h>

typedef unsigned short u16;
typedef unsigned int u32;
typedef __bf16 bf16x8 __attribute__((ext_vector_type(8)));
typedef float f32x4 __attribute__((ext_vector_type(4)));
typedef u16 u16x8 __attribute__((ext_vector_type(8)));
typedef u16 u16x4 __attribute__((ext_vector_type(4)));
typedef u32 u32x4 __attribute__((ext_vector_type(4)));

__device__ __forceinline__ u16 f2bf(float f){
  unsigned u = __float_as_uint(f);
  u += 0x7FFFu + ((u >> 16) & 1u);   // RNE
  return (u16)(u >> 16);
}
__device__ __forceinline__ float bf2f(u16 u){
  return __uint_as_float((u32)u << 16);
}
__device__ __forceinline__ u32 pack2bf(float a, float b){
  return (u32)f2bf(a) | ((u32)f2bf(b) << 16);
}
__device__ __forceinline__ void gload16(const void* g, void* l){
  __builtin_amdgcn_global_load_lds(
      (const __attribute__((address_space(1))) void*)g,
      (__attribute__((address_space(3))) void*)l, 16, 0, 0);
}

// ---------------- weight f32 [K][N] -> bf16 [drow0+N][K] (transposing convert) ----------------
__global__ __launch_bounds__(256) void conv_bf16_t(const float* __restrict__ src, u16* __restrict__ dst,
                                                   int K, int N, size_t dls, int drow0){
  __shared__ u16 s[64 * 68];
  size_t lo = (size_t)blockIdx.z * K * N;
  int n0 = blockIdx.x << 6, k0 = blockIdx.y << 6;
  int t = threadIdx.x;
#pragma unroll
  for (int p = 0; p < 4; ++p){
    int idx = p * 1024 + t * 4;
    int kl = idx >> 6, nl = idx & 63;
    f32x4 v = *(const f32x4*)(src + lo + (size_t)(k0 + kl) * N + n0 + nl);
#pragma unroll
    for (int j = 0; j < 4; ++j) s[(nl + j) * 68 + kl] = f2bf(v[j]);
  }
  __syncthreads();
  u16* db = dst + blockIdx.z * dls;
#pragma unroll
  for (int p = 0; p < 4; ++p){
    int idx = p * 1024 + t * 4;
    int nl = idx >> 6, kl = idx & 63;
    u16x4 o;
#pragma unroll
    for (int j = 0; j < 4; ++j) o[j] = s[nl * 68 + kl + j];
    *(u16x4*)(db + (size_t)(drow0 + n0 + nl) * K + k0 + kl) = o;
  }
}

// ---------------- plain f32 -> bf16 ----------------
__global__ __launch_bounds__(256) void conv_bf16(const float* __restrict__ src, u16* __restrict__ dst){
  size_t i = ((size_t)blockIdx.x * 256 + threadIdx.x) * 4;
  f32x4 v = *(const f32x4*)(src + i);
  u16x4 o;
#pragma unroll
  for (int j = 0; j < 4; ++j) o[j] = f2bf(v[j]);
  *(u16x4*)(dst + i) = o;
}

// ---------------- embedding + positional encoding ----------------
__global__ __launch_bounds__(256) void embed_k(const int* __restrict__ data, const float* __restrict__ emb,
                                               float* __restrict__ h, u16* __restrict__ hbf){
  int idx = blockIdx.x * 256 + threadIdx.x;       // 0 .. 2M-1
  int r = idx >> 10, d = idx & 1023;              // r = i*4+b
  int i = r >> 2;
  int e = data[r];
  float val = emb[(size_t)e * 1024 + d] * 32.0f;  // sqrt(1024)
  float pos = (float)(511 - i);
  int t = d & 511;
  float freq = powf(10000.0f, -(float)t * (1.0f / 512.0f));
  float ang = pos * freq;
  val += (d < 512) ? sinf(ang) : cosf(ang);
  h[idx] = val;
  hbf[idx] = f2bf(val);
}

// ---------------- bf16 MFMA GEMM: C = A[M,K] @ Bt[N,K]^T ----------------
// BK=64, 2-buffer R5 schedule, row&7 slot swizzle (both-sides). Cpart = bf16 partials.
// blockIdx.z = K-chunk (if Cpart) or batch (zA/zB/zC strides).
template<int BM>
__global__ __launch_bounds__(256) void gemm_bt(
    const u16* __restrict__ A, const u16* __restrict__ Bt,
    const float* __restrict__ bias, float* __restrict__ C, u16* __restrict__ Cbf,
    u16* __restrict__ Cpart, int M, int N, int K, int kchunk, int relu,
    size_t zA, size_t zB, size_t zC)
{
  constexpr int MFR = BM / 32;            // A frags per wave
  constexpr int ASZ = BM * 64, BSZ = 128 * 64;   // elements per buffer
  __shared__ __align__(16) u16 sA[2 * ASZ];
  __shared__ __align__(16) u16 sB[2 * BSZ];
  int tid = threadIdx.x, lane = tid & 63;
  int wr = (tid >> 7) & 1, wc = (tid >> 6) & 1;
  int m0 = blockIdx.y * BM, n0 = blockIdx.x << 7;
  int z = blockIdx.z;
  int kbeg = Cpart ? z * kchunk : 0;

  const u16* Ap = A + (size_t)z * zA;
  const u16* Bp = Bt + (size_t)z * zB;

  f32x4 acc[MFR][4];
#pragma unroll
  for (int i = 0; i < MFR; ++i)
#pragma unroll
    for (int j = 0; j < 4; ++j) acc[i][j] = (f32x4)(0.0f);

  int srow8 = tid >> 3;                   // 0..31
  int gslot8 = ((tid & 7) ^ (srow8 & 7)) << 3;
  const u16* Ab = Ap + (size_t)(m0 + srow8) * K + kbeg + gslot8;
  const u16* Bb = Bp + (size_t)(n0 + srow8) * K + kbeg + gslot8;
  const size_t rstep32 = (size_t)K << 5;  // 32 rows

  auto stage = [&](int buf, int k0){
#pragma unroll
    for (int p = 0; p < BM / 32; ++p)
      gload16(Ab + p * rstep32 + k0, (void*)&sA[buf * ASZ + p * 2048 + tid * 8]);
#pragma unroll
    for (int p = 0; p < 4; ++p)
      gload16(Bb + p * rstep32 + k0, (void*)&sB[buf * BSZ + p * 2048 + tid * 8]);
  };

  int r15 = lane & 15, g = lane >> 4;
  int s0 = g ^ (r15 & 7);
  const int o0 = s0 * 8, o1 = (s0 ^ 4) * 8;
  const int paBase = (wr * (BM / 2) + r15) * 64;
  const int pbBase = (wc * 64 + r15) * 64;

  int nk = kchunk >> 6;
  stage(0, 0);
  __syncthreads();
  for (int t = 0; t < nk; ++t){
    int cur = t & 1;
    if (t + 1 < nk) stage(cur ^ 1, (t + 1) << 6);
    const u16* pa = sA + cur * ASZ;
    const u16* pb = sB + cur * BSZ;
    bf16x8 af[MFR][2], bfv[4][2];
#pragma unroll
    for (int mi = 0; mi < MFR; ++mi){
      af[mi][0] = *(const bf16x8*)(pa + paBase + mi * 1024 + o0);
      af[mi][1] = *(const bf16x8*)(pa + paBase + mi * 1024 + o1);
    }
#pragma unroll
    for (int ni = 0; ni < 4; ++ni){
      bfv[ni][0] = *(const bf16x8*)(pb + pbBase + ni * 1024 + o0);
      bfv[ni][1] = *(const bf16x8*)(pb + pbBase + ni * 1024 + o1);
    }
#pragma unroll
    for (int kk = 0; kk < 2; ++kk)
#pragma unroll
      for (int mi = 0; mi < MFR; ++mi)
#pragma unroll
        for (int ni = 0; ni < 4; ++ni)
          acc[mi][ni] = __builtin_amdgcn_mfma_f32_16x16x32_bf16(af[mi][kk], bfv[ni][kk], acc[mi][ni], 0, 0, 0);
    __syncthreads();
  }

  int colf = lane & 15, rowf = (lane >> 4) << 2;
  if (Cpart){
    u16* dst = Cpart + (size_t)z * M * N;
#pragma unroll
    for (int ni = 0; ni < 4; ++ni){
      int cg = n0 + (wc << 6) + ni * 16 + colf;
#pragma unroll
      for (int mi = 0; mi < MFR; ++mi){
        int rg = m0 + wr * (BM / 2) + mi * 16 + rowf;
#pragma unroll
        for (int r = 0; r < 4; ++r)
          dst[(size_t)(rg + r) * N + cg] = f2bf(acc[mi][ni][r]);
      }
    }
  } else {
#pragma unroll
    for (int ni = 0; ni < 4; ++ni){
      int cg = n0 + (wc << 6) + ni * 16 + colf;
      float bv = bias ? bias[cg] : 0.0f;
#pragma unroll
      for (int mi = 0; mi < MFR; ++mi){
        int rg = m0 + wr * (BM / 2) + mi * 16 + rowf;
#pragma unroll
        for (int r = 0; r < 4; ++r){
          float val = acc[mi][ni][r] + bv;
          if (relu) val = fmaxf(val, 0.0f);
          size_t o = (size_t)(rg + r) * N + cg;
          if (C)   C[o]   = val;
          if (Cbf) (Cbf + (size_t)z * zC)[o] = f2bf(val);
        }
      }
    }
  }
}

// ---------------- V transpose into vtbf [bn][d][jdst0 + j] ----------------
__global__ __launch_bounds__(256) void vtrans(const u16* __restrict__ src, int sstride, int co,
                                              u16* __restrict__ dst, int jdst0,
                                              size_t zsrc, size_t zdst){
  __shared__ u16 s[64 * 68];
  int jt = blockIdx.x, bnp = blockIdx.y;
  int b = bnp >> 4, n = bnp & 15;
  int t = threadIdx.x;
  const u16* sp = src + blockIdx.z * zsrc;
  u16* dp = dst + blockIdx.z * zdst;
  int j0l = jt << 6;
#pragma unroll
  for (int rr = 0; rr < 16; ++rr){
    int idx = rr * 256 + t;
    int jl = idx >> 6, dd = idx & 63;
    s[jl * 68 + dd] = sp[(size_t)((j0l + jl) * 4 + b) * sstride + co + n * 128 + 64 + dd];
  }
  __syncthreads();
#pragma unroll
  for (int ww = 0; ww < 16; ++ww){
    int idx = ww * 256 + t;
    int dd = idx >> 6, jl = idx & 63;
    dp[((size_t)(bnp * 64 + dd) << 10) + jdst0 + j0l + jl] = s[jl * 68 + dd];
  }
}

// ---------------- MFMA flash attention (single-pass, dual-source K, LDS-staged) ----------------
// Block = 64 q-rows x one (b,n); 4 waves share double-buffered K/V tiles.
// kt<8: K from kvm (mems); kt>=8: K from qkv. Direct normalized bf16 output (no merge).
__global__ __launch_bounds__(256) void attn_mfma(
    const u16* __restrict__ qkv, const u16* __restrict__ kvm,
    const u16* __restrict__ vtbf, u16* __restrict__ attnbf)
{
  __shared__ __align__(16) u16 sK[2][64 * 64];
  __shared__ __align__(16) u16 sV[2][64 * 64];
  int tid = threadIdx.x, lane = tid & 63, wid = tid >> 6;
  int g = lane >> 4, t = lane & 15;
  int qt = blockIdx.x, bnp = blockIdx.y;
  int b = bnp >> 4, n = bnp & 15;
  int i0 = qt * 64 + wid * 16;
  int i = i0 + t;

  union Cvt { u32x4 u; bf16x8 v; };

  bf16x8 qfrag[2];
#pragma unroll
  for (int ks = 0; ks < 2; ++ks)
    qfrag[ks] = *(const bf16x8*)(qkv + (size_t)(i * 4 + b) * 3072 + n * 64 + ks * 32 + g * 8);

  f32x4 oacc[4];
#pragma unroll
  for (int df = 0; df < 4; ++df) oacc[df] = (f32x4)(0.0f);
  float mrun = -1e30f, lrun = 0.0f;

  const u16* kbm = kvm + n * 128;
  const u16* kbh = qkv + 1024 + n * 128;
  const u16* vb2 = vtbf + ((size_t)bnp << 16);   // rows d, stride 1024

  int srow = tid >> 3;                    // 0..31
  int gsl = ((tid & 7) ^ (srow & 7)) << 3;

  auto stageKV = [&](int buf, int kt){
    int j0 = kt << 6;
    const u16* kb = (kt < 8) ? kbm : kbh;
    size_t kst = (kt < 8) ? 2048 : 3072;
    int joff = (kt < 8) ? 0 : 512;
#pragma unroll
    for (int p = 0; p < 2; ++p){
      int jl = srow + p * 32;
      gload16(kb + (size_t)((j0 + jl - joff) * 4 + b) * kst + gsl, (void*)&sK[buf][p * 2048 + tid * 8]);
    }
#pragma unroll
    for (int p = 0; p < 2; ++p){
      int dl = srow + p * 32;
      gload16(vb2 + ((size_t)dl << 10) + j0 + gsl, (void*)&sV[buf][p * 2048 + tid * 8]);
    }
  };

  int kt1 = qt + 9;
  stageKV(0, 0);
  __syncthreads();
  for (int kt = 0; kt < kt1; ++kt){
    int cur = kt & 1;
    if (kt + 1 < kt1) stageKV(cur ^ 1, kt + 1);
    int j0 = kt << 6;
    f32x4 sacc[4];
#pragma unroll
    for (int jf = 0; jf < 4; ++jf) sacc[jf] = (f32x4)(0.0f);
#pragma unroll
    for (int ks = 0; ks < 2; ++ks){
      int sl = ((ks * 4 + g) ^ (t & 7)) * 8;
#pragma unroll
      for (int jf = 0; jf < 4; ++jf){
        bf16x8 kf = *(const bf16x8*)(&sK[cur][(jf * 16 + t) * 64 + sl]);
        sacc[jf] = __builtin_amdgcn_mfma_f32_16x16x32_bf16(kf, qfrag[ks], sacc[jf], 0, 0, 0);
      }
    }
    bool part = (j0 + 63 > i0 + 512);
    float ps[4][4];
    float tmax = -1e30f;
#pragma unroll
    for (int jf = 0; jf < 4; ++jf)
#pragma unroll
      for (int r = 0; r < 4; ++r){
        float s = sacc[jf][r] * 0.125f;
        if (part && (j0 + jf * 16 + g * 4 + r > i + 512)) s = -1e30f;
        ps[jf][r] = s;
        tmax = fmaxf(tmax, s);
      }
    tmax = fmaxf(tmax, __shfl_xor(tmax, 16));
    tmax = fmaxf(tmax, __shfl_xor(tmax, 32));
    float mnew = fmaxf(mrun, tmax);
    float sc = __expf(mrun - mnew);
    mrun = mnew;
    lrun *= sc;
    u32 pk0[2], pk1[2], pk2[2], pk3[2];
    {
      float e0, e1, e2, e3;
#define DO_JF(PK, JF) \
      e0 = __expf(ps[JF][0] - mnew); e1 = __expf(ps[JF][1] - mnew); \
      e2 = __expf(ps[JF][2] - mnew); e3 = __expf(ps[JF][3] - mnew); \
      lrun += (e0 + e1) + (e2 + e3); \
      PK[0] = pack2bf(e0, e1); PK[1] = pack2bf(e2, e3);
      DO_JF(pk0, 0) DO_JF(pk1, 1) DO_JF(pk2, 2) DO_JF(pk3, 3)
#undef DO_JF
    }
#pragma unroll
    for (int df = 0; df < 4; ++df)
#pragma unroll
      for (int r = 0; r < 4; ++r) oacc[df][r] *= sc;

    int srcA = t + 16 * ((2 * g) & 3);
    int srcB = t + 16 * ((2 * g + 1) & 3);
    bool ghi = (g >= 2);
#pragma unroll
    for (int ks = 0; ks < 2; ++ks){
      u32 w0a, w1a, w2a, w3a, w0b, w1b, w2b, w3b;
      if (ks == 0){
        w0a = __shfl((int)pk0[0], srcA); w1a = __shfl((int)pk0[1], srcA);
        w2a = __shfl((int)pk0[0], srcB); w3a = __shfl((int)pk0[1], srcB);
        w0b = __shfl((int)pk1[0], srcA); w1b = __shfl((int)pk1[1], srcA);
        w2b = __shfl((int)pk1[0], srcB); w3b = __shfl((int)pk1[1], srcB);
      } else {
        w0a = __shfl((int)pk2[0], srcA); w1a = __shfl((int)pk2[1], srcA);
        w2a = __shfl((int)pk2[0], srcB); w3a = __shfl((int)pk2[1], srcB);
        w0b = __shfl((int)pk3[0], srcA); w1b = __shfl((int)pk3[1], srcA);
        w2b = __shfl((int)pk3[0], srcB); w3b = __shfl((int)pk3[1], srcB);
      }
      Cvt c;
      c.u[0] = ghi ? w0b : w0a;
      c.u[1] = ghi ? w1b : w1a;
      c.u[2] = ghi ? w2b : w2a;
      c.u[3] = ghi ? w3b : w3a;
      bf16x8 pf = c.v;
      int sl = ((ks * 4 + g) ^ (t & 7)) * 8;
#pragma unroll
      for (int df = 0; df < 4; ++df){
        bf16x8 vf = *(const bf16x8*)(&sV[cur][(df * 16 + t) * 64 + sl]);
        oacc[df] = __builtin_amdgcn_mfma_f32_16x16x32_bf16(vf, pf, oacc[df], 0, 0, 0);
      }
    }
    __syncthreads();
  }
  lrun += __shfl_xor(lrun, 16);
  lrun += __shfl_xor(lrun, 32);
  float inv = 1.0f / lrun;

  u16* orow = attnbf + ((size_t)(i * 4 + b) << 10) + n * 64;
#pragma unroll
  for (int df = 0; df < 4; ++df){
#pragma unroll
    for (int h = 0; h < 2; ++h){
      *(u32*)(orow + df * 16 + g * 4 + 2 * h) = pack2bf(oacc[df][2 * h] * inv, oacc[df][2 * h + 1] * inv);
    }
  }
}

// ---------------- residual + (bf16 split-K partial sum) + bias + layernorm ----------------
__global__ __launch_bounds__(256) void ln_k(const float* __restrict__ res, const u16* __restrict__ parts,
                                            size_t pstride, int np, const float* __restrict__ bias,
                                            const float* __restrict__ g, const float* __restrict__ bta,
                                            float* hout, u16* __restrict__ hbf)
{
  int row = blockIdx.x, tid = threadIdx.x;
  int d0 = tid << 2;
  size_t ro = (size_t)row << 10;
  f32x4 v = *(const f32x4*)(res + ro + d0);
  if (bias){
    f32x4 bv = *(const f32x4*)(bias + d0);
#pragma unroll
    for (int j = 0; j < 4; ++j) v[j] += bv[j];
  }
  for (int p = 0; p < np; ++p){
    u16x4 pv = *(const u16x4*)(parts + p * pstride + ro + d0);
#pragma unroll
    for (int j = 0; j < 4; ++j) v[j] += bf2f(pv[j]);
  }
  float s = (v[0] + v[1]) + (v[2] + v[3]);
  float s2 = (v[0] * v[0] + v[1] * v[1]) + (v[2] * v[2] + v[3] * v[3]);
#pragma unroll
  for (int off = 32; off; off >>= 1){ s += __shfl_xor(s, off); s2 += __shfl_xor(s2, off); }
  __shared__ float ps[8];
  int wid = tid >> 6, lane = tid & 63;
  if (lane == 0){ ps[wid] = s; ps[wid + 4] = s2; }
  __syncthreads();
  s  = ps[0] + ps[1] + ps[2] + ps[3];
  s2 = ps[4] + ps[5] + ps[6] + ps[7];
  float mu = s * 0.0009765625f;
  float var = s2 * 0.0009765625f - mu * mu;
  float rstd = rsqrtf(var + 1e-5f);
  f32x4 gv = *(const f32x4*)(g + d0);
  f32x4 bt = *(const f32x4*)(bta + d0);
  f32x4 ho;
  u16x4 hb;
#pragma unroll
  for (int j = 0; j < 4; ++j){
    float tv = (v[j] - mu) * rstd * gv[j] + bt[j];
    ho[j] = tv; hb[j] = f2bf(tv);
  }
  *(f32x4*)(hout + ro + d0) = ho;
  *(u16x4*)(hbf + ro + d0) = hb;
}

__global__ __launch_bounds__(256) void copy_f32(const f32x4* __restrict__ src, f32x4* __restrict__ dst){
  size_t i = (size_t)blockIdx.x * 256 + threadIdx.x;
  dst[i] = src[i];
}

extern "C" void kernel_launch(void* const* d_in, const int* in_sizes, int n_in,
                              void* d_out, int out_size, void* d_ws, size_t ws_size,
                              hipStream_t stream)
{
  const int*   data = (const int*)  d_in[0];
  const float* mems = (const float*)d_in[1];
  const float* emb  = (const float*)d_in[2];
  const float* Wq   = (const float*)d_in[3];
  const float* Wkv  = (const float*)d_in[4];
  const float* Wo   = (const float*)d_in[5];
  const float* ln1g = (const float*)d_in[6];
  const float* ln1b = (const float*)d_in[7];
  const float* W1   = (const float*)d_in[8];
  const float* b1   = (const float*)d_in[9];
  const float* W2   = (const float*)d_in[10];
  const float* b2   = (const float*)d_in[11];
  const float* ln2g = (const float*)d_in[12];
  const float* ln2b = (const float*)d_in[13];
  float* out = (float*)d_out;

  char* ws = (char*)d_ws;
  size_t off = 0;
  auto alloc = [&](size_t bytes) -> char* {
    char* p = ws + off;
    off = (off + bytes + 255) & ~(size_t)255;
    return p;
  };

  // fused transposed QKV weights: [l][3072][1024] (rows 0..1023 = Wq^T, 1024..3071 = Wkv^T)
  u16*   wqkv_bf = (u16*) alloc((size_t)6 * 3072 * 1024 * 2);
  u16*   wo_bf   = (u16*) alloc((size_t)6 * 1024 * 1024 * 2);
  u16*   w1_bf   = (u16*) alloc((size_t)6 * 4096 * 1024 * 2);
  u16*   w2_bf   = (u16*) alloc((size_t)6 * 1024 * 4096 * 2);
  u16*   memsbf  = (u16*) alloc((size_t)6 * 2048 * 1024 * 2);
  u16*   kvmem   = (u16*) alloc((size_t)6 * 2048 * 2048 * 2);   // per-layer mems-KV
  u16*   vtbf    = (u16*) alloc((size_t)6 * 64 * 64 * 1024 * 2);
  float* h       = (float*)alloc((size_t)2048 * 1024 * 4);
  u16*   hbf     = (u16*) alloc((size_t)2048 * 1024 * 2);
  u16*   qkv     = (u16*) alloc((size_t)2048 * 3072 * 2);
  u16*   attnbf  = (u16*) alloc((size_t)2048 * 1024 * 2);
  u16*   f1bf    = (u16*) alloc((size_t)2048 * 4096 * 2);
  u16*   pbf     = (u16*) alloc((size_t)4 * 2048 * 1024 * 2);   // bf16 split-K partials
  const size_t PS = (size_t)2048 * 1024;
  const size_t VTL = (size_t)64 * 64 * 1024;

  // ---- layer-independent preamble (full-chip parallel) ----
  conv_bf16_t<<<dim3(16, 16, 6), 256, 0, stream>>>(Wq,  wqkv_bf, 1024, 1024, (size_t)3072 * 1024, 0);
  conv_bf16_t<<<dim3(32, 16, 6), 256, 0, stream>>>(Wkv, wqkv_bf, 1024, 2048, (size_t)3072 * 1024, 1024);
  conv_bf16_t<<<dim3(16, 16, 6), 256, 0, stream>>>(Wo,  wo_bf,   1024, 1024, (size_t)1024 * 1024, 0);
  conv_bf16_t<<<dim3(64, 16, 6), 256, 0, stream>>>(W1,  w1_bf,   1024, 4096, (size_t)4096 * 1024, 0);
  conv_bf16_t<<<dim3(16, 64, 6), 256, 0, stream>>>(W2,  w2_bf,   4096, 1024, (size_t)4096 * 1024, 0);
  conv_bf16<<<12288, 256, 0, stream>>>(mems, memsbf);
  embed_k<<<8192, 256, 0, stream>>>(data, emb, h, hbf);
  // batched mems-KV GEMM for all 6 layers (BM=128): kvmem[l] = memsbf[l] @ Wkv[l]
  gemm_bt<128><<<dim3(16, 16, 6), 256, 0, stream>>>(memsbf, wqkv_bf + (size_t)1024 * 1024, nullptr,
      nullptr, kvmem, nullptr, 2048, 2048, 1024, 1024, 0,
      (size_t)2048 * 1024, (size_t)3072 * 1024, (size_t)2048 * 2048);
  // mems-V transpose for all layers (j < 512)
  vtrans<<<dim3(8, 64, 6), 256, 0, stream>>>(kvmem, 2048, 0, vtbf, 0, (size_t)2048 * 2048, VTL);

  for (int l = 0; l < 6; ++l){
    u16* kvm_l = kvmem + (size_t)l * 2048 * 2048;
    u16* vt_l  = vtbf + (size_t)l * VTL;
    // fused Q/KV(h) GEMM (BM=64, 768 blocks = even 3/CU): qkv[2048][3072]
    gemm_bt<64><<<dim3(24, 32), 256, 0, stream>>>(hbf, wqkv_bf + (size_t)l * 3072 * 1024, nullptr,
        nullptr, qkv, nullptr, 2048, 3072, 1024, 1024, 0, 0, 0, 0);
    // h-part V transpose (j >= 512)
    vtrans<<<dim3(8, 64), 256, 0, stream>>>(qkv, 3072, 1024, vt_l, 512, 0, 0);
    // attention: single-pass, LDS-staged, direct output
    attn_mfma<<<dim3(8, 64), 256, 0, stream>>>(qkv, kvm_l, vt_l, attnbf);
    // Wo: split-K x2 -> bf16 partials, summed inside ln1
    gemm_bt<64><<<dim3(8, 32, 2), 256, 0, stream>>>(attnbf, wo_bf + (size_t)l * 1024 * 1024, nullptr,
        nullptr, nullptr, pbf, 2048, 1024, 1024, 512, 0, 0, 0, 0);
    ln_k<<<2048, 256, 0, stream>>>(h, pbf, PS, 2, nullptr, ln1g + l * 1024, ln1b + l * 1024, h, hbf);
    // W1 + bias + relu (BM=128, 512 blocks = even 2/CU)
    gemm_bt<128><<<dim3(32, 16), 256, 0, stream>>>(hbf, w1_bf + (size_t)l * 4096 * 1024,
        b1 + (size_t)l * 4096, nullptr, f1bf, nullptr, 2048, 4096, 1024, 1024, 1, 0, 0, 0);
    // W2: split-K x4 -> bf16 partials, summed (+b2) inside ln2
    gemm_bt<64><<<dim3(8, 32, 4), 256, 0, stream>>>(f1bf, w2_bf + (size_t)l * 4096 * 1024, nullptr,
        nullptr, nullptr, pbf, 2048, 1024, 4096, 1024, 0, 0, 0, 0);
    ln_k<<<2048, 256, 0, stream>>>(h, pbf, PS, 4, b2 + l * 1024, ln2g + l * 1024, ln2b + l * 1024, h, hbf);
  }
  copy_f32<<<2048, 256, 0, stream>>>((const f32x4*)h, (f32x4*)out);
}

// Round 13
// 1062.419 us; speedup vs baseline: 1.4692x; 1.1000x over previous
//
#include <hip/hip_runtime.h>

typedef unsigned short u16;
typedef unsigned int u32;
typedef __bf16 bf16x8 __attribute__((ext_vector_type(8)));
typedef float f32x4 __attribute__((ext_vector_type(4)));
typedef u16 u16x8 __attribute__((ext_vector_type(8)));
typedef u16 u16x4 __attribute__((ext_vector_type(4)));
typedef u32 u32x4 __attribute__((ext_vector_type(4)));

__device__ __forceinline__ u16 f2bf(float f){
  unsigned u = __float_as_uint(f);
  u += 0x7FFFu + ((u >> 16) & 1u);   // RNE
  return (u16)(u >> 16);
}
__device__ __forceinline__ float bf2f(u16 u){
  return __uint_as_float((u32)u << 16);
}
__device__ __forceinline__ u32 pack2bf(float a, float b){
  return (u32)f2bf(a) | ((u32)f2bf(b) << 16);
}
__device__ __forceinline__ void gload16(const void* g, void* l){
  __builtin_amdgcn_global_load_lds(
      (const __attribute__((address_space(1))) void*)g,
      (__attribute__((address_space(3))) void*)l, 16, 0, 0);
}

// ---------------- weight f32 [K][N] -> bf16 [drow0+N][K] (transposing convert) ----------------
__global__ __launch_bounds__(256) void conv_bf16_t(const float* __restrict__ src, u16* __restrict__ dst,
                                                   int K, int N, size_t dls, int drow0){
  __shared__ u16 s[64 * 68];
  size_t lo = (size_t)blockIdx.z * K * N;
  int n0 = blockIdx.x << 6, k0 = blockIdx.y << 6;
  int t = threadIdx.x;
#pragma unroll
  for (int p = 0; p < 4; ++p){
    int idx = p * 1024 + t * 4;
    int kl = idx >> 6, nl = idx & 63;
    f32x4 v = *(const f32x4*)(src + lo + (size_t)(k0 + kl) * N + n0 + nl);
#pragma unroll
    for (int j = 0; j < 4; ++j) s[(nl + j) * 68 + kl] = f2bf(v[j]);
  }
  __syncthreads();
  u16* db = dst + blockIdx.z * dls;
#pragma unroll
  for (int p = 0; p < 4; ++p){
    int idx = p * 1024 + t * 4;
    int nl = idx >> 6, kl = idx & 63;
    u16x4 o;
#pragma unroll
    for (int j = 0; j < 4; ++j) o[j] = s[nl * 68 + kl + j];
    *(u16x4*)(db + (size_t)(drow0 + n0 + nl) * K + k0 + kl) = o;
  }
}

// ---------------- plain f32 -> bf16 ----------------
__global__ __launch_bounds__(256) void conv_bf16(const float* __restrict__ src, u16* __restrict__ dst){
  size_t i = ((size_t)blockIdx.x * 256 + threadIdx.x) * 4;
  f32x4 v = *(const f32x4*)(src + i);
  u16x4 o;
#pragma unroll
  for (int j = 0; j < 4; ++j) o[j] = f2bf(v[j]);
  *(u16x4*)(dst + i) = o;
}

// ---------------- embedding + positional encoding (bf16 residual only) ----------------
__global__ __launch_bounds__(256) void embed_k(const int* __restrict__ data, const float* __restrict__ emb,
                                               u16* __restrict__ hbf){
  int idx = blockIdx.x * 256 + threadIdx.x;       // 0 .. 2M-1
  int r = idx >> 10, d = idx & 1023;              // r = i*4+b
  int i = r >> 2;
  int e = data[r];
  float val = emb[(size_t)e * 1024 + d] * 32.0f;  // sqrt(1024)
  float pos = (float)(511 - i);
  int t = d & 511;
  float freq = powf(10000.0f, -(float)t * (1.0f / 512.0f));
  float ang = pos * freq;
  val += (d < 512) ? sinf(ang) : cosf(ang);
  hbf[idx] = f2bf(val);
}

// ---------------- bf16 MFMA GEMM: C = A[M,K] @ Bt[N,K]^T ----------------
// BK=64, 2-buffer R5 schedule, row&7 slot swizzle (both-sides). Cpart = bf16 partials.
// blockIdx.z = K-chunk (if Cpart) or batch (zA/zB/zC strides).
template<int BM>
__global__ __launch_bounds__(256) void gemm_bt(
    const u16* __restrict__ A, const u16* __restrict__ Bt,
    const float* __restrict__ bias, float* __restrict__ C, u16* __restrict__ Cbf,
    u16* __restrict__ Cpart, int M, int N, int K, int kchunk, int relu,
    size_t zA, size_t zB, size_t zC)
{
  constexpr int MFR = BM / 32;            // A frags per wave
  constexpr int ASZ = BM * 64, BSZ = 128 * 64;   // elements per buffer
  __shared__ __align__(16) u16 sA[2 * ASZ];
  __shared__ __align__(16) u16 sB[2 * BSZ];
  int tid = threadIdx.x, lane = tid & 63;
  int wr = (tid >> 7) & 1, wc = (tid >> 6) & 1;
  int m0 = blockIdx.y * BM, n0 = blockIdx.x << 7;
  int z = blockIdx.z;
  int kbeg = Cpart ? z * kchunk : 0;

  const u16* Ap = A + (size_t)z * zA;
  const u16* Bp = Bt + (size_t)z * zB;

  f32x4 acc[MFR][4];
#pragma unroll
  for (int i = 0; i < MFR; ++i)
#pragma unroll
    for (int j = 0; j < 4; ++j) acc[i][j] = (f32x4)(0.0f);

  int srow8 = tid >> 3;                   // 0..31
  int gslot8 = ((tid & 7) ^ (srow8 & 7)) << 3;
  const u16* Ab = Ap + (size_t)(m0 + srow8) * K + kbeg + gslot8;
  const u16* Bb = Bp + (size_t)(n0 + srow8) * K + kbeg + gslot8;
  const size_t rstep32 = (size_t)K << 5;  // 32 rows

  auto stage = [&](int buf, int k0){
#pragma unroll
    for (int p = 0; p < BM / 32; ++p)
      gload16(Ab + p * rstep32 + k0, (void*)&sA[buf * ASZ + p * 2048 + tid * 8]);
#pragma unroll
    for (int p = 0; p < 4; ++p)
      gload16(Bb + p * rstep32 + k0, (void*)&sB[buf * BSZ + p * 2048 + tid * 8]);
  };

  int r15 = lane & 15, g = lane >> 4;
  int s0 = g ^ (r15 & 7);
  const int o0 = s0 * 8, o1 = (s0 ^ 4) * 8;
  const int paBase = (wr * (BM / 2) + r15) * 64;
  const int pbBase = (wc * 64 + r15) * 64;

  int nk = kchunk >> 6;
  stage(0, 0);
  __syncthreads();
  for (int t = 0; t < nk; ++t){
    int cur = t & 1;
    if (t + 1 < nk) stage(cur ^ 1, (t + 1) << 6);
    const u16* pa = sA + cur * ASZ;
    const u16* pb = sB + cur * BSZ;
    bf16x8 af[MFR][2], bfv[4][2];
#pragma unroll
    for (int mi = 0; mi < MFR; ++mi){
      af[mi][0] = *(const bf16x8*)(pa + paBase + mi * 1024 + o0);
      af[mi][1] = *(const bf16x8*)(pa + paBase + mi * 1024 + o1);
    }
#pragma unroll
    for (int ni = 0; ni < 4; ++ni){
      bfv[ni][0] = *(const bf16x8*)(pb + pbBase + ni * 1024 + o0);
      bfv[ni][1] = *(const bf16x8*)(pb + pbBase + ni * 1024 + o1);
    }
#pragma unroll
    for (int kk = 0; kk < 2; ++kk)
#pragma unroll
      for (int mi = 0; mi < MFR; ++mi)
#pragma unroll
        for (int ni = 0; ni < 4; ++ni)
          acc[mi][ni] = __builtin_amdgcn_mfma_f32_16x16x32_bf16(af[mi][kk], bfv[ni][kk], acc[mi][ni], 0, 0, 0);
    __syncthreads();
  }

  int colf = lane & 15, rowf = (lane >> 4) << 2;
  if (Cpart){
    u16* dst = Cpart + (size_t)z * M * N;
#pragma unroll
    for (int ni = 0; ni < 4; ++ni){
      int cg = n0 + (wc << 6) + ni * 16 + colf;
#pragma unroll
      for (int mi = 0; mi < MFR; ++mi){
        int rg = m0 + wr * (BM / 2) + mi * 16 + rowf;
#pragma unroll
        for (int r = 0; r < 4; ++r)
          dst[(size_t)(rg + r) * N + cg] = f2bf(acc[mi][ni][r]);
      }
    }
  } else {
#pragma unroll
    for (int ni = 0; ni < 4; ++ni){
      int cg = n0 + (wc << 6) + ni * 16 + colf;
      float bv = bias ? bias[cg] : 0.0f;
#pragma unroll
      for (int mi = 0; mi < MFR; ++mi){
        int rg = m0 + wr * (BM / 2) + mi * 16 + rowf;
#pragma unroll
        for (int r = 0; r < 4; ++r){
          float val = acc[mi][ni][r] + bv;
          if (relu) val = fmaxf(val, 0.0f);
          size_t o = (size_t)(rg + r) * N + cg;
          if (C)   C[o]   = val;
          if (Cbf) (Cbf + (size_t)z * zC)[o] = f2bf(val);
        }
      }
    }
  }
}

// ---------------- V transpose into vtbf [bn][d][jdst0 + j] ----------------
__global__ __launch_bounds__(256) void vtrans(const u16* __restrict__ src, int sstride, int co,
                                              u16* __restrict__ dst, int jdst0,
                                              size_t zsrc, size_t zdst){
  __shared__ u16 s[64 * 68];
  int jt = blockIdx.x, bnp = blockIdx.y;
  int b = bnp >> 4, n = bnp & 15;
  int t = threadIdx.x;
  const u16* sp = src + blockIdx.z * zsrc;
  u16* dp = dst + blockIdx.z * zdst;
  int j0l = jt << 6;
#pragma unroll
  for (int rr = 0; rr < 16; ++rr){
    int idx = rr * 256 + t;
    int jl = idx >> 6, dd = idx & 63;
    s[jl * 68 + dd] = sp[(size_t)((j0l + jl) * 4 + b) * sstride + co + n * 128 + 64 + dd];
  }
  __syncthreads();
#pragma unroll
  for (int ww = 0; ww < 16; ++ww){
    int idx = ww * 256 + t;
    int dd = idx >> 6, jl = idx & 63;
    dp[((size_t)(bnp * 64 + dd) << 10) + jdst0 + j0l + jl] = s[jl * 68 + dd];
  }
}

// ---------------- MFMA flash attention (single-pass, dual-source K, LDS-staged) ----------------
__global__ __launch_bounds__(256) void attn_mfma(
    const u16* __restrict__ qkv, const u16* __restrict__ kvm,
    const u16* __restrict__ vtbf, u16* __restrict__ attnbf)
{
  __shared__ __align__(16) u16 sK[2][64 * 64];
  __shared__ __align__(16) u16 sV[2][64 * 64];
  int tid = threadIdx.x, lane = tid & 63, wid = tid >> 6;
  int g = lane >> 4, t = lane & 15;
  int qt = blockIdx.x, bnp = blockIdx.y;
  int b = bnp >> 4, n = bnp & 15;
  int i0 = qt * 64 + wid * 16;
  int i = i0 + t;

  union Cvt { u32x4 u; bf16x8 v; };

  bf16x8 qfrag[2];
#pragma unroll
  for (int ks = 0; ks < 2; ++ks)
    qfrag[ks] = *(const bf16x8*)(qkv + (size_t)(i * 4 + b) * 3072 + n * 64 + ks * 32 + g * 8);

  f32x4 oacc[4];
#pragma unroll
  for (int df = 0; df < 4; ++df) oacc[df] = (f32x4)(0.0f);
  float mrun = -1e30f, lrun = 0.0f;

  const u16* kbm = kvm + n * 128;
  const u16* kbh = qkv + 1024 + n * 128;
  const u16* vb2 = vtbf + ((size_t)bnp << 16);   // rows d, stride 1024

  int srow = tid >> 3;                    // 0..31
  int gsl = ((tid & 7) ^ (srow & 7)) << 3;

  auto stageKV = [&](int buf, int kt){
    int j0 = kt << 6;
    const u16* kb = (kt < 8) ? kbm : kbh;
    size_t kst = (kt < 8) ? 2048 : 3072;
    int joff = (kt < 8) ? 0 : 512;
#pragma unroll
    for (int p = 0; p < 2; ++p){
      int jl = srow + p * 32;
      gload16(kb + (size_t)((j0 + jl - joff) * 4 + b) * kst + gsl, (void*)&sK[buf][p * 2048 + tid * 8]);
    }
#pragma unroll
    for (int p = 0; p < 2; ++p){
      int dl = srow + p * 32;
      gload16(vb2 + ((size_t)dl << 10) + j0 + gsl, (void*)&sV[buf][p * 2048 + tid * 8]);
    }
  };

  int kt1 = qt + 9;
  stageKV(0, 0);
  __syncthreads();
  for (int kt = 0; kt < kt1; ++kt){
    int cur = kt & 1;
    if (kt + 1 < kt1) stageKV(cur ^ 1, kt + 1);
    int j0 = kt << 6;
    f32x4 sacc[4];
#pragma unroll
    for (int jf = 0; jf < 4; ++jf) sacc[jf] = (f32x4)(0.0f);
#pragma unroll
    for (int ks = 0; ks < 2; ++ks){
      int sl = ((ks * 4 + g) ^ (t & 7)) * 8;
#pragma unroll
      for (int jf = 0; jf < 4; ++jf){
        bf16x8 kf = *(const bf16x8*)(&sK[cur][(jf * 16 + t) * 64 + sl]);
        sacc[jf] = __builtin_amdgcn_mfma_f32_16x16x32_bf16(kf, qfrag[ks], sacc[jf], 0, 0, 0);
      }
    }
    bool part = (j0 + 63 > i0 + 512);
    float ps[4][4];
    float tmax = -1e30f;
#pragma unroll
    for (int jf = 0; jf < 4; ++jf)
#pragma unroll
      for (int r = 0; r < 4; ++r){
        float s = sacc[jf][r] * 0.125f;
        if (part && (j0 + jf * 16 + g * 4 + r > i + 512)) s = -1e30f;
        ps[jf][r] = s;
        tmax = fmaxf(tmax, s);
      }
    tmax = fmaxf(tmax, __shfl_xor(tmax, 16));
    tmax = fmaxf(tmax, __shfl_xor(tmax, 32));
    float mnew = fmaxf(mrun, tmax);
    float sc = __expf(mrun - mnew);
    mrun = mnew;
    lrun *= sc;
    u32 pk0[2], pk1[2], pk2[2], pk3[2];
    {
      float e0, e1, e2, e3;
#define DO_JF(PK, JF) \
      e0 = __expf(ps[JF][0] - mnew); e1 = __expf(ps[JF][1] - mnew); \
      e2 = __expf(ps[JF][2] - mnew); e3 = __expf(ps[JF][3] - mnew); \
      lrun += (e0 + e1) + (e2 + e3); \
      PK[0] = pack2bf(e0, e1); PK[1] = pack2bf(e2, e3);
      DO_JF(pk0, 0) DO_JF(pk1, 1) DO_JF(pk2, 2) DO_JF(pk3, 3)
#undef DO_JF
    }
#pragma unroll
    for (int df = 0; df < 4; ++df)
#pragma unroll
      for (int r = 0; r < 4; ++r) oacc[df][r] *= sc;

    int srcA = t + 16 * ((2 * g) & 3);
    int srcB = t + 16 * ((2 * g + 1) & 3);
    bool ghi = (g >= 2);
#pragma unroll
    for (int ks = 0; ks < 2; ++ks){
      u32 w0a, w1a, w2a, w3a, w0b, w1b, w2b, w3b;
      if (ks == 0){
        w0a = __shfl((int)pk0[0], srcA); w1a = __shfl((int)pk0[1], srcA);
        w2a = __shfl((int)pk0[0], srcB); w3a = __shfl((int)pk0[1], srcB);
        w0b = __shfl((int)pk1[0], srcA); w1b = __shfl((int)pk1[1], srcA);
        w2b = __shfl((int)pk1[0], srcB); w3b = __shfl((int)pk1[1], srcB);
      } else {
        w0a = __shfl((int)pk2[0], srcA); w1a = __shfl((int)pk2[1], srcA);
        w2a = __shfl((int)pk2[0], srcB); w3a = __shfl((int)pk2[1], srcB);
        w0b = __shfl((int)pk3[0], srcA); w1b = __shfl((int)pk3[1], srcA);
        w2b = __shfl((int)pk3[0], srcB); w3b = __shfl((int)pk3[1], srcB);
      }
      Cvt c;
      c.u[0] = ghi ? w0b : w0a;
      c.u[1] = ghi ? w1b : w1a;
      c.u[2] = ghi ? w2b : w2a;
      c.u[3] = ghi ? w3b : w3a;
      bf16x8 pf = c.v;
      int sl = ((ks * 4 + g) ^ (t & 7)) * 8;
#pragma unroll
      for (int df = 0; df < 4; ++df){
        bf16x8 vf = *(const bf16x8*)(&sV[cur][(df * 16 + t) * 64 + sl]);
        oacc[df] = __builtin_amdgcn_mfma_f32_16x16x32_bf16(vf, pf, oacc[df], 0, 0, 0);
      }
    }
    __syncthreads();
  }
  lrun += __shfl_xor(lrun, 16);
  lrun += __shfl_xor(lrun, 32);
  float inv = 1.0f / lrun;

  u16* orow = attnbf + ((size_t)(i * 4 + b) << 10) + n * 64;
#pragma unroll
  for (int df = 0; df < 4; ++df){
#pragma unroll
    for (int h = 0; h < 2; ++h){
      *(u32*)(orow + df * 16 + g * 4 + 2 * h) = pack2bf(oacc[df][2 * h] * inv, oacc[df][2 * h + 1] * inv);
    }
  }
}

// ---------------- bf16 residual + (bf16 split-K partial sum) + bias + layernorm ----------------
// Writes bf16 hbf (in-place-safe: each thread reads its own elems first); optionally f32 out.
__global__ __launch_bounds__(256) void ln_k(const u16* __restrict__ resbf, const u16* __restrict__ parts,
                                            size_t pstride, int np, const float* __restrict__ bias,
                                            const float* __restrict__ g, const float* __restrict__ bta,
                                            u16* __restrict__ hbf, float* __restrict__ fout)
{
  int row = blockIdx.x, tid = threadIdx.x;
  int d0 = tid << 2;
  size_t ro = (size_t)row << 10;
  u16x4 rv = *(const u16x4*)(resbf + ro + d0);
  f32x4 v;
#pragma unroll
  for (int j = 0; j < 4; ++j) v[j] = bf2f(rv[j]);
  if (bias){
    f32x4 bv = *(const f32x4*)(bias + d0);
#pragma unroll
    for (int j = 0; j < 4; ++j) v[j] += bv[j];
  }
  for (int p = 0; p < np; ++p){
    u16x4 pv = *(const u16x4*)(parts + p * pstride + ro + d0);
#pragma unroll
    for (int j = 0; j < 4; ++j) v[j] += bf2f(pv[j]);
  }
  float s = (v[0] + v[1]) + (v[2] + v[3]);
  float s2 = (v[0] * v[0] + v[1] * v[1]) + (v[2] * v[2] + v[3] * v[3]);
#pragma unroll
  for (int off = 32; off; off >>= 1){ s += __shfl_xor(s, off); s2 += __shfl_xor(s2, off); }
  __shared__ float ps[8];
  int wid = tid >> 6, lane = tid & 63;
  if (lane == 0){ ps[wid] = s; ps[wid + 4] = s2; }
  __syncthreads();
  s  = ps[0] + ps[1] + ps[2] + ps[3];
  s2 = ps[4] + ps[5] + ps[6] + ps[7];
  float mu = s * 0.0009765625f;
  float var = s2 * 0.0009765625f - mu * mu;
  float rstd = rsqrtf(var + 1e-5f);
  f32x4 gv = *(const f32x4*)(g + d0);
  f32x4 bt = *(const f32x4*)(bta + d0);
  f32x4 fo;
  u16x4 hb;
#pragma unroll
  for (int j = 0; j < 4; ++j){
    float tv = (v[j] - mu) * rstd * gv[j] + bt[j];
    fo[j] = tv; hb[j] = f2bf(tv);
  }
  *(u16x4*)(hbf + ro + d0) = hb;
  if (fout) *(f32x4*)(fout + ro + d0) = fo;
}

extern "C" void kernel_launch(void* const* d_in, const int* in_sizes, int n_in,
                              void* d_out, int out_size, void* d_ws, size_t ws_size,
                              hipStream_t stream)
{
  const int*   data = (const int*)  d_in[0];
  const float* mems = (const float*)d_in[1];
  const float* emb  = (const float*)d_in[2];
  const float* Wq   = (const float*)d_in[3];
  const float* Wkv  = (const float*)d_in[4];
  const float* Wo   = (const float*)d_in[5];
  const float* ln1g = (const float*)d_in[6];
  const float* ln1b = (const float*)d_in[7];
  const float* W1   = (const float*)d_in[8];
  const float* b1   = (const float*)d_in[9];
  const float* W2   = (const float*)d_in[10];
  const float* b2   = (const float*)d_in[11];
  const float* ln2g = (const float*)d_in[12];
  const float* ln2b = (const float*)d_in[13];
  float* out = (float*)d_out;

  char* ws = (char*)d_ws;
  size_t off = 0;
  auto alloc = [&](size_t bytes) -> char* {
    char* p = ws + off;
    off = (off + bytes + 255) & ~(size_t)255;
    return p;
  };

  // fused transposed QKV weights: [l][3072][1024] (rows 0..1023 = Wq^T, 1024..3071 = Wkv^T)
  u16*   wqkv_bf = (u16*) alloc((size_t)6 * 3072 * 1024 * 2);
  u16*   wo_bf   = (u16*) alloc((size_t)6 * 1024 * 1024 * 2);
  u16*   w1_bf   = (u16*) alloc((size_t)6 * 4096 * 1024 * 2);
  u16*   w2_bf   = (u16*) alloc((size_t)6 * 1024 * 4096 * 2);
  u16*   memsbf  = (u16*) alloc((size_t)6 * 2048 * 1024 * 2);
  u16*   kvmem   = (u16*) alloc((size_t)6 * 2048 * 2048 * 2);   // per-layer mems-KV
  u16*   vtbf    = (u16*) alloc((size_t)6 * 64 * 64 * 1024 * 2);
  u16*   hbf     = (u16*) alloc((size_t)2048 * 1024 * 2);
  u16*   qkv     = (u16*) alloc((size_t)2048 * 3072 * 2);
  u16*   attnbf  = (u16*) alloc((size_t)2048 * 1024 * 2);
  u16*   f1bf    = (u16*) alloc((size_t)2048 * 4096 * 2);
  u16*   pbf     = (u16*) alloc((size_t)4 * 2048 * 1024 * 2);   // bf16 split-K partials
  const size_t PS = (size_t)2048 * 1024;
  const size_t VTL = (size_t)64 * 64 * 1024;

  // ---- layer-independent preamble (full-chip parallel) ----
  conv_bf16_t<<<dim3(16, 16, 6), 256, 0, stream>>>(Wq,  wqkv_bf, 1024, 1024, (size_t)3072 * 1024, 0);
  conv_bf16_t<<<dim3(32, 16, 6), 256, 0, stream>>>(Wkv, wqkv_bf, 1024, 2048, (size_t)3072 * 1024, 1024);
  conv_bf16_t<<<dim3(16, 16, 6), 256, 0, stream>>>(Wo,  wo_bf,   1024, 1024, (size_t)1024 * 1024, 0);
  conv_bf16_t<<<dim3(64, 16, 6), 256, 0, stream>>>(W1,  w1_bf,   1024, 4096, (size_t)4096 * 1024, 0);
  conv_bf16_t<<<dim3(16, 64, 6), 256, 0, stream>>>(W2,  w2_bf,   4096, 1024, (size_t)4096 * 1024, 0);
  conv_bf16<<<12288, 256, 0, stream>>>(mems, memsbf);
  embed_k<<<8192, 256, 0, stream>>>(data, emb, hbf);
  // batched mems-KV GEMM for all 6 layers (BM=128): kvmem[l] = memsbf[l] @ Wkv[l]
  gemm_bt<128><<<dim3(16, 16, 6), 256, 0, stream>>>(memsbf, wqkv_bf + (size_t)1024 * 1024, nullptr,
      nullptr, kvmem, nullptr, 2048, 2048, 1024, 1024, 0,
      (size_t)2048 * 1024, (size_t)3072 * 1024, (size_t)2048 * 2048);
  // mems-V transpose for all layers (j < 512)
  vtrans<<<dim3(8, 64, 6), 256, 0, stream>>>(kvmem, 2048, 0, vtbf, 0, (size_t)2048 * 2048, VTL);

  for (int l = 0; l < 6; ++l){
    u16* kvm_l = kvmem + (size_t)l * 2048 * 2048;
    u16* vt_l  = vtbf + (size_t)l * VTL;
    // fused Q/KV(h) GEMM (BM=64, 768 blocks = even 3/CU): qkv[2048][3072]
    gemm_bt<64><<<dim3(24, 32), 256, 0, stream>>>(hbf, wqkv_bf + (size_t)l * 3072 * 1024, nullptr,
        nullptr, qkv, nullptr, 2048, 3072, 1024, 1024, 0, 0, 0, 0);
    // h-part V transpose (j >= 512)
    vtrans<<<dim3(8, 64), 256, 0, stream>>>(qkv, 3072, 1024, vt_l, 512, 0, 0);
    // attention: single-pass, LDS-staged, direct output
    attn_mfma<<<dim3(8, 64), 256, 0, stream>>>(qkv, kvm_l, vt_l, attnbf);
    // Wo: split-K x2 -> bf16 partials, summed inside ln1
    gemm_bt<64><<<dim3(8, 32, 2), 256, 0, stream>>>(attnbf, wo_bf + (size_t)l * 1024 * 1024, nullptr,
        nullptr, nullptr, pbf, 2048, 1024, 1024, 512, 0, 0, 0, 0);
    ln_k<<<2048, 256, 0, stream>>>(hbf, pbf, PS, 2, nullptr, ln1g + l * 1024, ln1b + l * 1024, hbf, nullptr);
    // W1 + bias + relu (BM=128, 512 blocks = even 2/CU)
    gemm_bt<128><<<dim3(32, 16), 256, 0, stream>>>(hbf, w1_bf + (size_t)l * 4096 * 1024,
        b1 + (size_t)l * 4096, nullptr, f1bf, nullptr, 2048, 4096, 1024, 1024, 1, 0, 0, 0);
    // W2: split-K x4 -> bf16 partials (BM=128, 512 blocks = 2/CU), summed (+b2) inside ln2
    gemm_bt<128><<<dim3(8, 16, 4), 256, 0, stream>>>(f1bf, w2_bf + (size_t)l * 4096 * 1024, nullptr,
        nullptr, nullptr, pbf, 2048, 1024, 4096, 1024, 0, 0, 0, 0);
    ln_k<<<2048, 256, 0, stream>>>(hbf, pbf, PS, 4, b2 + l * 1024, ln2g + l * 1024, ln2b + l * 1024,
                                   hbf, (l == 5) ? out : nullptr);
  }
}

// Round 14
// 1036.225 us; speedup vs baseline: 1.5063x; 1.0253x over previous
//
#include <hip/hip_runtime.h>

typedef unsigned short u16;
typedef unsigned int u32;
typedef __bf16 bf16x8 __attribute__((ext_vector_type(8)));
typedef float f32x4 __attribute__((ext_vector_type(4)));
typedef u16 u16x8 __attribute__((ext_vector_type(8)));
typedef u16 u16x4 __attribute__((ext_vector_type(4)));
typedef u32 u32x4 __attribute__((ext_vector_type(4)));

__device__ __forceinline__ u16 f2bf(float f){
  unsigned u = __float_as_uint(f);
  u += 0x7FFFu + ((u >> 16) & 1u);   // RNE
  return (u16)(u >> 16);
}
__device__ __forceinline__ float bf2f(u16 u){
  return __uint_as_float((u32)u << 16);
}
__device__ __forceinline__ u32 pack2bf(float a, float b){
  return (u32)f2bf(a) | ((u32)f2bf(b) << 16);
}
__device__ __forceinline__ void gload16(const void* g, void* l){
  __builtin_amdgcn_global_load_lds(
      (const __attribute__((address_space(1))) void*)g,
      (__attribute__((address_space(3))) void*)l, 16, 0, 0);
}

// ---------------- weight f32 [K][N] -> bf16 [drow0+N][K] (transposing convert) ----------------
__global__ __launch_bounds__(256) void conv_bf16_t(const float* __restrict__ src, u16* __restrict__ dst,
                                                   int K, int N, size_t dls, int drow0){
  __shared__ u16 s[64 * 68];
  size_t lo = (size_t)blockIdx.z * K * N;
  int n0 = blockIdx.x << 6, k0 = blockIdx.y << 6;
  int t = threadIdx.x;
#pragma unroll
  for (int p = 0; p < 4; ++p){
    int idx = p * 1024 + t * 4;
    int kl = idx >> 6, nl = idx & 63;
    f32x4 v = *(const f32x4*)(src + lo + (size_t)(k0 + kl) * N + n0 + nl);
#pragma unroll
    for (int j = 0; j < 4; ++j) s[(nl + j) * 68 + kl] = f2bf(v[j]);
  }
  __syncthreads();
  u16* db = dst + blockIdx.z * dls;
#pragma unroll
  for (int p = 0; p < 4; ++p){
    int idx = p * 1024 + t * 4;
    int nl = idx >> 6, kl = idx & 63;
    u16x4 o;
#pragma unroll
    for (int j = 0; j < 4; ++j) o[j] = s[nl * 68 + kl + j];
    *(u16x4*)(db + (size_t)(drow0 + n0 + nl) * K + k0 + kl) = o;
  }
}

// ---------------- plain f32 -> bf16 ----------------
__global__ __launch_bounds__(256) void conv_bf16(const float* __restrict__ src, u16* __restrict__ dst){
  size_t i = ((size_t)blockIdx.x * 256 + threadIdx.x) * 4;
  f32x4 v = *(const f32x4*)(src + i);
  u16x4 o;
#pragma unroll
  for (int j = 0; j < 4; ++j) o[j] = f2bf(v[j]);
  *(u16x4*)(dst + i) = o;
}

// ---------------- embedding + positional encoding (bf16 residual only) ----------------
__global__ __launch_bounds__(256) void embed_k(const int* __restrict__ data, const float* __restrict__ emb,
                                               u16* __restrict__ hbf){
  int idx = blockIdx.x * 256 + threadIdx.x;       // 0 .. 2M-1
  int r = idx >> 10, d = idx & 1023;              // r = i*4+b
  int i = r >> 2;
  int e = data[r];
  float val = emb[(size_t)e * 1024 + d] * 32.0f;  // sqrt(1024)
  float pos = (float)(511 - i);
  int t = d & 511;
  float freq = powf(10000.0f, -(float)t * (1.0f / 512.0f));
  float ang = pos * freq;
  val += (d < 512) ? sinf(ang) : cosf(ang);
  hbf[idx] = f2bf(val);
}

// ---------------- bf16 MFMA GEMM: C = A[M,K] @ Bt[N,K]^T ----------------
// BK=64, 2-buffer schedule, row&7 slot swizzle. Cpart = bf16 split-K partials.
// VT: fused V-transpose epilogue — N-tiles with n0>=vcol0 are one head's [K|V];
// wc==1 waves route V-half via LDS to VT[(b*16+n)*64+d][jdst0 + m0/4 + jj] (skip C-write).
template<int BM>
__global__ __launch_bounds__(256) void gemm_bt(
    const u16* __restrict__ A, const u16* __restrict__ Bt,
    const float* __restrict__ bias, float* __restrict__ C, u16* __restrict__ Cbf,
    u16* __restrict__ Cpart, int M, int N, int K, int kchunk, int relu,
    size_t zA, size_t zB, size_t zC,
    u16* __restrict__ VT, size_t zVT, int vcol0, int jdst0)
{
  constexpr int MFR = BM / 32;            // A frags per wave
  constexpr int ASZ = BM * 64, BSZ = 128 * 64;   // elements per buffer
  __shared__ __align__(16) u16 sA[2 * ASZ];
  __shared__ __align__(16) u16 sB[2 * BSZ];
  int tid = threadIdx.x, lane = tid & 63;
  int wr = (tid >> 7) & 1, wc = (tid >> 6) & 1;
  int m0 = blockIdx.y * BM, n0 = blockIdx.x << 7;
  int z = blockIdx.z;
  int kbeg = Cpart ? z * kchunk : 0;

  const u16* Ap = A + (size_t)z * zA;
  const u16* Bp = Bt + (size_t)z * zB;

  f32x4 acc[MFR][4];
#pragma unroll
  for (int i = 0; i < MFR; ++i)
#pragma unroll
    for (int j = 0; j < 4; ++j) acc[i][j] = (f32x4)(0.0f);

  int srow8 = tid >> 3;                   // 0..31
  int gslot8 = ((tid & 7) ^ (srow8 & 7)) << 3;
  const u16* Ab = Ap + (size_t)(m0 + srow8) * K + kbeg + gslot8;
  const u16* Bb = Bp + (size_t)(n0 + srow8) * K + kbeg + gslot8;
  const size_t rstep32 = (size_t)K << 5;  // 32 rows

  auto stage = [&](int buf, int k0){
#pragma unroll
    for (int p = 0; p < BM / 32; ++p)
      gload16(Ab + p * rstep32 + k0, (void*)&sA[buf * ASZ + p * 2048 + tid * 8]);
#pragma unroll
    for (int p = 0; p < 4; ++p)
      gload16(Bb + p * rstep32 + k0, (void*)&sB[buf * BSZ + p * 2048 + tid * 8]);
  };

  int r15 = lane & 15, g = lane >> 4;
  int s0 = g ^ (r15 & 7);
  const int o0 = s0 * 8, o1 = (s0 ^ 4) * 8;
  const int paBase = (wr * (BM / 2) + r15) * 64;
  const int pbBase = (wc * 64 + r15) * 64;

  int nk = kchunk >> 6;
  stage(0, 0);
  __syncthreads();
  for (int t = 0; t < nk; ++t){
    int cur = t & 1;
    if (t + 1 < nk) stage(cur ^ 1, (t + 1) << 6);
    const u16* pa = sA + cur * ASZ;
    const u16* pb = sB + cur * BSZ;
    bf16x8 af[MFR][2], bfv[4][2];
#pragma unroll
    for (int mi = 0; mi < MFR; ++mi){
      af[mi][0] = *(const bf16x8*)(pa + paBase + mi * 1024 + o0);
      af[mi][1] = *(const bf16x8*)(pa + paBase + mi * 1024 + o1);
    }
#pragma unroll
    for (int ni = 0; ni < 4; ++ni){
      bfv[ni][0] = *(const bf16x8*)(pb + pbBase + ni * 1024 + o0);
      bfv[ni][1] = *(const bf16x8*)(pb + pbBase + ni * 1024 + o1);
    }
#pragma unroll
    for (int kk = 0; kk < 2; ++kk)
#pragma unroll
      for (int mi = 0; mi < MFR; ++mi)
#pragma unroll
        for (int ni = 0; ni < 4; ++ni)
          acc[mi][ni] = __builtin_amdgcn_mfma_f32_16x16x32_bf16(af[mi][kk], bfv[ni][kk], acc[mi][ni], 0, 0, 0);
    __syncthreads();
  }

  int colf = lane & 15, rowf = (lane >> 4) << 2;
  bool vtile = (VT != nullptr) && (n0 >= vcol0);
  if (Cpart){
    u16* dst = Cpart + (size_t)z * M * N;
#pragma unroll
    for (int ni = 0; ni < 4; ++ni){
      int cg = n0 + (wc << 6) + ni * 16 + colf;
#pragma unroll
      for (int mi = 0; mi < MFR; ++mi){
        int rg = m0 + wr * (BM / 2) + mi * 16 + rowf;
#pragma unroll
        for (int r = 0; r < 4; ++r)
          dst[(size_t)(rg + r) * N + cg] = f2bf(acc[mi][ni][r]);
      }
    }
  } else {
    if (!(vtile && wc == 1)){
#pragma unroll
      for (int ni = 0; ni < 4; ++ni){
        int cg = n0 + (wc << 6) + ni * 16 + colf;
        float bv = bias ? bias[cg] : 0.0f;
#pragma unroll
        for (int mi = 0; mi < MFR; ++mi){
          int rg = m0 + wr * (BM / 2) + mi * 16 + rowf;
#pragma unroll
          for (int r = 0; r < 4; ++r){
            float val = acc[mi][ni][r] + bv;
            if (relu) val = fmaxf(val, 0.0f);
            size_t o = (size_t)(rg + r) * N + cg;
            if (C)   C[o]   = val;
            if (Cbf) (Cbf + (size_t)z * zC)[o] = f2bf(val);
          }
        }
      }
    }
    if (vtile){
      // V-half (wc==1 waves) -> LDS [row][68] -> transposed write to VT
      if (wc == 1){
#pragma unroll
        for (int ni = 0; ni < 4; ++ni)
#pragma unroll
          for (int mi = 0; mi < MFR; ++mi)
#pragma unroll
            for (int r = 0; r < 4; ++r)
              sA[(wr * (BM / 2) + mi * 16 + rowf + r) * 68 + ni * 16 + colf] = f2bf(acc[mi][ni][r]);
      }
      __syncthreads();
      int vb = tid >> 6, vd = tid & 63;
      int nh = (n0 - vcol0) >> 7;
      u16* dst = VT + (size_t)z * zVT + (((size_t)((vb << 4) + nh) << 6) + vd) * 1024 + jdst0 + (m0 >> 2);
      u16 tmp[BM / 4];
#pragma unroll
      for (int jj = 0; jj < BM / 4; ++jj) tmp[jj] = sA[((jj << 2) + vb) * 68 + vd];
#pragma unroll
      for (int c = 0; c < BM / 32; ++c)
        *(u16x8*)(dst + c * 8) = *(const u16x8*)(&tmp[c * 8]);
    }
  }
}

// ---------------- MFMA flash attention (single-pass, dual-source K, LDS-staged) ----------------
__global__ __launch_bounds__(256) void attn_mfma(
    const u16* __restrict__ qkv, const u16* __restrict__ kvm,
    const u16* __restrict__ vtbf, u16* __restrict__ attnbf)
{
  __shared__ __align__(16) u16 sK[2][64 * 64];
  __shared__ __align__(16) u16 sV[2][64 * 64];
  int tid = threadIdx.x, lane = tid & 63, wid = tid >> 6;
  int g = lane >> 4, t = lane & 15;
  int qt = blockIdx.x, bnp = blockIdx.y;
  int b = bnp >> 4, n = bnp & 15;
  int i0 = qt * 64 + wid * 16;
  int i = i0 + t;

  union Cvt { u32x4 u; bf16x8 v; };

  bf16x8 qfrag[2];
#pragma unroll
  for (int ks = 0; ks < 2; ++ks)
    qfrag[ks] = *(const bf16x8*)(qkv + (size_t)(i * 4 + b) * 3072 + n * 64 + ks * 32 + g * 8);

  f32x4 oacc[4];
#pragma unroll
  for (int df = 0; df < 4; ++df) oacc[df] = (f32x4)(0.0f);
  float mrun = -1e30f, lrun = 0.0f;

  const u16* kbm = kvm + n * 128;
  const u16* kbh = qkv + 1024 + n * 128;
  const u16* vb2 = vtbf + ((size_t)bnp << 16);   // rows d, stride 1024

  int srow = tid >> 3;                    // 0..31
  int gsl = ((tid & 7) ^ (srow & 7)) << 3;

  auto stageKV = [&](int buf, int kt){
    int j0 = kt << 6;
    const u16* kb = (kt < 8) ? kbm : kbh;
    size_t kst = (kt < 8) ? 2048 : 3072;
    int joff = (kt < 8) ? 0 : 512;
#pragma unroll
    for (int p = 0; p < 2; ++p){
      int jl = srow + p * 32;
      gload16(kb + (size_t)((j0 + jl - joff) * 4 + b) * kst + gsl, (void*)&sK[buf][p * 2048 + tid * 8]);
    }
#pragma unroll
    for (int p = 0; p < 2; ++p){
      int dl = srow + p * 32;
      gload16(vb2 + ((size_t)dl << 10) + j0 + gsl, (void*)&sV[buf][p * 2048 + tid * 8]);
    }
  };

  int kt1 = qt + 9;
  stageKV(0, 0);
  __syncthreads();
  for (int kt = 0; kt < kt1; ++kt){
    int cur = kt & 1;
    if (kt + 1 < kt1) stageKV(cur ^ 1, kt + 1);
    int j0 = kt << 6;
    f32x4 sacc[4];
#pragma unroll
    for (int jf = 0; jf < 4; ++jf) sacc[jf] = (f32x4)(0.0f);
#pragma unroll
    for (int ks = 0; ks < 2; ++ks){
      int sl = ((ks * 4 + g) ^ (t & 7)) * 8;
#pragma unroll
      for (int jf = 0; jf < 4; ++jf){
        bf16x8 kf = *(const bf16x8*)(&sK[cur][(jf * 16 + t) * 64 + sl]);
        sacc[jf] = __builtin_amdgcn_mfma_f32_16x16x32_bf16(kf, qfrag[ks], sacc[jf], 0, 0, 0);
      }
    }
    bool part = (j0 + 63 > i0 + 512);
    float ps[4][4];
    float tmax = -1e30f;
#pragma unroll
    for (int jf = 0; jf < 4; ++jf)
#pragma unroll
      for (int r = 0; r < 4; ++r){
        float s = sacc[jf][r] * 0.125f;
        if (part && (j0 + jf * 16 + g * 4 + r > i + 512)) s = -1e30f;
        ps[jf][r] = s;
        tmax = fmaxf(tmax, s);
      }
    tmax = fmaxf(tmax, __shfl_xor(tmax, 16));
    tmax = fmaxf(tmax, __shfl_xor(tmax, 32));
    float mnew = fmaxf(mrun, tmax);
    float sc = __expf(mrun - mnew);
    mrun = mnew;
    lrun *= sc;
    u32 pk0[2], pk1[2], pk2[2], pk3[2];
    {
      float e0, e1, e2, e3;
#define DO_JF(PK, JF) \
      e0 = __expf(ps[JF][0] - mnew); e1 = __expf(ps[JF][1] - mnew); \
      e2 = __expf(ps[JF][2] - mnew); e3 = __expf(ps[JF][3] - mnew); \
      lrun += (e0 + e1) + (e2 + e3); \
      PK[0] = pack2bf(e0, e1); PK[1] = pack2bf(e2, e3);
      DO_JF(pk0, 0) DO_JF(pk1, 1) DO_JF(pk2, 2) DO_JF(pk3, 3)
#undef DO_JF
    }
#pragma unroll
    for (int df = 0; df < 4; ++df)
#pragma unroll
      for (int r = 0; r < 4; ++r) oacc[df][r] *= sc;

    int srcA = t + 16 * ((2 * g) & 3);
    int srcB = t + 16 * ((2 * g + 1) & 3);
    bool ghi = (g >= 2);
#pragma unroll
    for (int ks = 0; ks < 2; ++ks){
      u32 w0a, w1a, w2a, w3a, w0b, w1b, w2b, w3b;
      if (ks == 0){
        w0a = __shfl((int)pk0[0], srcA); w1a = __shfl((int)pk0[1], srcA);
        w2a = __shfl((int)pk0[0], srcB); w3a = __shfl((int)pk0[1], srcB);
        w0b = __shfl((int)pk1[0], srcA); w1b = __shfl((int)pk1[1], srcA);
        w2b = __shfl((int)pk1[0], srcB); w3b = __shfl((int)pk1[1], srcB);
      } else {
        w0a = __shfl((int)pk2[0], srcA); w1a = __shfl((int)pk2[1], srcA);
        w2a = __shfl((int)pk2[0], srcB); w3a = __shfl((int)pk2[1], srcB);
        w0b = __shfl((int)pk3[0], srcA); w1b = __shfl((int)pk3[1], srcA);
        w2b = __shfl((int)pk3[0], srcB); w3b = __shfl((int)pk3[1], srcB);
      }
      Cvt c;
      c.u[0] = ghi ? w0b : w0a;
      c.u[1] = ghi ? w1b : w1a;
      c.u[2] = ghi ? w2b : w2a;
      c.u[3] = ghi ? w3b : w3a;
      bf16x8 pf = c.v;
      int sl = ((ks * 4 + g) ^ (t & 7)) * 8;
#pragma unroll
      for (int df = 0; df < 4; ++df){
        bf16x8 vf = *(const bf16x8*)(&sV[cur][(df * 16 + t) * 64 + sl]);
        oacc[df] = __builtin_amdgcn_mfma_f32_16x16x32_bf16(vf, pf, oacc[df], 0, 0, 0);
      }
    }
    __syncthreads();
  }
  lrun += __shfl_xor(lrun, 16);
  lrun += __shfl_xor(lrun, 32);
  float inv = 1.0f / lrun;

  u16* orow = attnbf + ((size_t)(i * 4 + b) << 10) + n * 64;
#pragma unroll
  for (int df = 0; df < 4; ++df){
#pragma unroll
    for (int h = 0; h < 2; ++h){
      *(u32*)(orow + df * 16 + g * 4 + 2 * h) = pack2bf(oacc[df][2 * h] * inv, oacc[df][2 * h + 1] * inv);
    }
  }
}

// ---------------- bf16 residual + (bf16 split-K partial sum) + bias + layernorm ----------------
__global__ __launch_bounds__(256) void ln_k(const u16* __restrict__ resbf, const u16* __restrict__ parts,
                                            size_t pstride, int np, const float* __restrict__ bias,
                                            const float* __restrict__ g, const float* __restrict__ bta,
                                            u16* __restrict__ hbf, float* __restrict__ fout)
{
  int row = blockIdx.x, tid = threadIdx.x;
  int d0 = tid << 2;
  size_t ro = (size_t)row << 10;
  u16x4 rv = *(const u16x4*)(resbf + ro + d0);
  f32x4 v;
#pragma unroll
  for (int j = 0; j < 4; ++j) v[j] = bf2f(rv[j]);
  if (bias){
    f32x4 bv = *(const f32x4*)(bias + d0);
#pragma unroll
    for (int j = 0; j < 4; ++j) v[j] += bv[j];
  }
  for (int p = 0; p < np; ++p){
    u16x4 pv = *(const u16x4*)(parts + p * pstride + ro + d0);
#pragma unroll
    for (int j = 0; j < 4; ++j) v[j] += bf2f(pv[j]);
  }
  float s = (v[0] + v[1]) + (v[2] + v[3]);
  float s2 = (v[0] * v[0] + v[1] * v[1]) + (v[2] * v[2] + v[3] * v[3]);
#pragma unroll
  for (int off = 32; off; off >>= 1){ s += __shfl_xor(s, off); s2 += __shfl_xor(s2, off); }
  __shared__ float ps[8];
  int wid = tid >> 6, lane = tid & 63;
  if (lane == 0){ ps[wid] = s; ps[wid + 4] = s2; }
  __syncthreads();
  s  = ps[0] + ps[1] + ps[2] + ps[3];
  s2 = ps[4] + ps[5] + ps[6] + ps[7];
  float mu = s * 0.0009765625f;
  float var = s2 * 0.0009765625f - mu * mu;
  float rstd = rsqrtf(var + 1e-5f);
  f32x4 gv = *(const f32x4*)(g + d0);
  f32x4 bt = *(const f32x4*)(bta + d0);
  f32x4 fo;
  u16x4 hb;
#pragma unroll
  for (int j = 0; j < 4; ++j){
    float tv = (v[j] - mu) * rstd * gv[j] + bt[j];
    fo[j] = tv; hb[j] = f2bf(tv);
  }
  *(u16x4*)(hbf + ro + d0) = hb;
  if (fout) *(f32x4*)(fout + ro + d0) = fo;
}

extern "C" void kernel_launch(void* const* d_in, const int* in_sizes, int n_in,
                              void* d_out, int out_size, void* d_ws, size_t ws_size,
                              hipStream_t stream)
{
  const int*   data = (const int*)  d_in[0];
  const float* mems = (const float*)d_in[1];
  const float* emb  = (const float*)d_in[2];
  const float* Wq   = (const float*)d_in[3];
  const float* Wkv  = (const float*)d_in[4];
  const float* Wo   = (const float*)d_in[5];
  const float* ln1g = (const float*)d_in[6];
  const float* ln1b = (const float*)d_in[7];
  const float* W1   = (const float*)d_in[8];
  const float* b1   = (const float*)d_in[9];
  const float* W2   = (const float*)d_in[10];
  const float* b2   = (const float*)d_in[11];
  const float* ln2g = (const float*)d_in[12];
  const float* ln2b = (const float*)d_in[13];
  float* out = (float*)d_out;

  char* ws = (char*)d_ws;
  size_t off = 0;
  auto alloc = [&](size_t bytes) -> char* {
    char* p = ws + off;
    off = (off + bytes + 255) & ~(size_t)255;
    return p;
  };

  // fused transposed QKV weights: [l][3072][1024] (rows 0..1023 = Wq^T, 1024..3071 = Wkv^T)
  u16*   wqkv_bf = (u16*) alloc((size_t)6 * 3072 * 1024 * 2);
  u16*   wo_bf   = (u16*) alloc((size_t)6 * 1024 * 1024 * 2);
  u16*   w1_bf   = (u16*) alloc((size_t)6 * 4096 * 1024 * 2);
  u16*   w2_bf   = (u16*) alloc((size_t)6 * 1024 * 4096 * 2);
  u16*   memsbf  = (u16*) alloc((size_t)6 * 2048 * 1024 * 2);
  u16*   kvmem   = (u16*) alloc((size_t)6 * 2048 * 2048 * 2);   // per-layer mems-KV (K part used)
  u16*   vtbf    = (u16*) alloc((size_t)6 * 64 * 64 * 1024 * 2);
  u16*   hbf     = (u16*) alloc((size_t)2048 * 1024 * 2);
  u16*   qkv     = (u16*) alloc((size_t)2048 * 3072 * 2);
  u16*   attnbf  = (u16*) alloc((size_t)2048 * 1024 * 2);
  u16*   f1bf    = (u16*) alloc((size_t)2048 * 4096 * 2);
  u16*   pbf     = (u16*) alloc((size_t)4 * 2048 * 1024 * 2);   // bf16 split-K partials
  const size_t PS = (size_t)2048 * 1024;
  const size_t VTL = (size_t)64 * 64 * 1024;

  // ---- layer-independent preamble (full-chip parallel) ----
  conv_bf16_t<<<dim3(16, 16, 6), 256, 0, stream>>>(Wq,  wqkv_bf, 1024, 1024, (size_t)3072 * 1024, 0);
  conv_bf16_t<<<dim3(32, 16, 6), 256, 0, stream>>>(Wkv, wqkv_bf, 1024, 2048, (size_t)3072 * 1024, 1024);
  conv_bf16_t<<<dim3(16, 16, 6), 256, 0, stream>>>(Wo,  wo_bf,   1024, 1024, (size_t)1024 * 1024, 0);
  conv_bf16_t<<<dim3(64, 16, 6), 256, 0, stream>>>(W1,  w1_bf,   1024, 4096, (size_t)4096 * 1024, 0);
  conv_bf16_t<<<dim3(16, 64, 6), 256, 0, stream>>>(W2,  w2_bf,   4096, 1024, (size_t)4096 * 1024, 0);
  conv_bf16<<<12288, 256, 0, stream>>>(mems, memsbf);
  embed_k<<<8192, 256, 0, stream>>>(data, emb, hbf);
  // batched mems-KV GEMM (BM=128) with fused V-transpose: K -> kvmem, V -> vtbf[j<512]
  gemm_bt<128><<<dim3(16, 16, 6), 256, 0, stream>>>(memsbf, wqkv_bf + (size_t)1024 * 1024, nullptr,
      nullptr, kvmem, nullptr, 2048, 2048, 1024, 1024, 0,
      (size_t)2048 * 1024, (size_t)3072 * 1024, (size_t)2048 * 2048,
      vtbf, VTL, 0, 0);

  for (int l = 0; l < 6; ++l){
    u16* kvm_l = kvmem + (size_t)l * 2048 * 2048;
    u16* vt_l  = vtbf + (size_t)l * VTL;
    // fused Q/KV(h) GEMM (BM=64) with fused V-transpose: Q,K -> qkv, V -> vtbf[j>=512]
    gemm_bt<64><<<dim3(24, 32), 256, 0, stream>>>(hbf, wqkv_bf + (size_t)l * 3072 * 1024, nullptr,
        nullptr, qkv, nullptr, 2048, 3072, 1024, 1024, 0, 0, 0, 0,
        vt_l, 0, 1024, 512);
    // attention: single-pass, LDS-staged, direct output
    attn_mfma<<<dim3(8, 64), 256, 0, stream>>>(qkv, kvm_l, vt_l, attnbf);
    // Wo: split-K x2 -> bf16 partials, summed inside ln1
    gemm_bt<64><<<dim3(8, 32, 2), 256, 0, stream>>>(attnbf, wo_bf + (size_t)l * 1024 * 1024, nullptr,
        nullptr, nullptr, pbf, 2048, 1024, 1024, 512, 0, 0, 0, 0,
        nullptr, 0, 0, 0);
    ln_k<<<2048, 256, 0, stream>>>(hbf, pbf, PS, 2, nullptr, ln1g + l * 1024, ln1b + l * 1024, hbf, nullptr);
    // W1 + bias + relu (BM=128)
    gemm_bt<128><<<dim3(32, 16), 256, 0, stream>>>(hbf, w1_bf + (size_t)l * 4096 * 1024,
        b1 + (size_t)l * 4096, nullptr, f1bf, nullptr, 2048, 4096, 1024, 1024, 1, 0, 0, 0,
        nullptr, 0, 0, 0);
    // W2: split-K x4 -> bf16 partials (BM=128), summed (+b2) inside ln2
    gemm_bt<128><<<dim3(8, 16, 4), 256, 0, stream>>>(f1bf, w2_bf + (size_t)l * 4096 * 1024, nullptr,
        nullptr, nullptr, pbf, 2048, 1024, 4096, 1024, 0, 0, 0, 0,
        nullptr, 0, 0, 0);
    ln_k<<<2048, 256, 0, stream>>>(hbf, pbf, PS, 4, b2 + l * 1024, ln2g + l * 1024, ln2b + l * 1024,
                                   hbf, (l == 5) ? out : nullptr);
  }
}